// Round 14
// baseline (173.014 us; speedup 1.0000x reference)
//
#include <hip/hip_runtime.h>
#include <math.h>

#define H 256
#define COLSN 64
#define ROWSN 200000
#define T_STEPS 4
#define QLEN 40
#define NNUM 5
#define NOPS 9

// workspace float offsets
#define WS_UBUF   0          // 4*768 u slices (reuses XWB region; temporally disjoint)
#define WS_XWB    0          // 40*256 (k_pre -> k_rnn)
#define WS_Q      10240      // 256
#define WS_AOP    10496      // 4*16
#define WS_ACOL   10560      // 4*64
#define WS_PIV    10816      // [0]=g [1]=l
#define WS_TICKET 10818
#define WS_PACC8  10824      // 8
#define WS_MDONE  10837
#define WS_MOP    11104      // 9*256 (MOP+MCOL contiguous 73*256)
#define WS_MCOL   13408      // 64*256 (ends 29792)
#define WS_WFLAG  30000      // 12 flags, one per 32-float (128B) line

#define NTBL_TILES  1563
#define NTBL_BLOCKS 782
#define NW 12                // sel workers
#define NMB 72               // M blocks
#define NSELF (NW + NMB)     // 84

template<int CTRL>
__device__ __forceinline__ float dpp_add(float x) {
    int xi = __float_as_int(x);
    int yi = __builtin_amdgcn_update_dpp(0, xi, CTRL, 0xF, 0xF, true);
    return x + __int_as_float(yi);
}
#define DPP_XOR1 0xB1
#define DPP_XOR2 0x4E
#define DPP_HMIR 0x141
#define DPP_MIR  0x140

__device__ __forceinline__ float reduce16(float v) {
    v = dpp_add<DPP_XOR1>(v);
    v = dpp_add<DPP_XOR2>(v);
    v = dpp_add<DPP_HMIR>(v);
    v = dpp_add<DPP_MIR>(v);
    return v;
}

__device__ __forceinline__ float fast_tanh(float x) {
    float cx = fminf(15.f, fmaxf(-15.f, x));
    float e = __expf(2.f * cx);
    return __fdividef(e - 1.f, e + 1.f);
}

__device__ __forceinline__ float dot4(float4 a, float4 b) {
    return a.x * b.x + a.y * b.y + a.z * b.z + a.w * b.w;
}

// device-coherent data movement WITHOUT RMW:
__device__ __forceinline__ float aload(const float* p) {
    return __hip_atomic_load(p, __ATOMIC_RELAXED, __HIP_MEMORY_SCOPE_AGENT);
}
__device__ __forceinline__ void astore(float* p, float v) {
    __hip_atomic_store(p, v, __ATOMIC_RELAXED, __HIP_MEMORY_SCOPE_AGENT);
}
__device__ __forceinline__ float flag_acq(const float* p) {
    return __hip_atomic_load(p, __ATOMIC_ACQUIRE, __HIP_MEMORY_SCOPE_AGENT);
}
__device__ __forceinline__ void flag_rel_store(float* p, float v) {
    __hip_atomic_store(p, v, __ATOMIC_RELEASE, __HIP_MEMORY_SCOPE_AGENT);
}
__device__ __forceinline__ void flag_rel_add(float* p, float v) {
    __hip_atomic_fetch_add(p, v, __ATOMIC_RELEASE, __HIP_MEMORY_SCOPE_AGENT);
}

// LDS swizzle: +4 floats pad per 16
__device__ __forceinline__ int sw(int i) { return i + ((i >> 4) << 2); }

// ==== k_pre: 10 blocks x 1024 -> X@Wx+b; blk0 zeroes flags ====
__global__ __launch_bounds__(1024) void k_pre(const int* __restrict__ iq,
        const float* __restrict__ E, const float* __restrict__ Wx,
        const float* __restrict__ b, float* __restrict__ ws) {
    int tid = threadIdx.x;
    if (blockIdx.x == 0) {
        if (tid < 22) ws[WS_TICKET + tid] = 0.f;            // ticket, PACC8, MDONE
        if (tid >= 32 && tid < 32 + NW) ws[WS_WFLAG + (tid - 32) * 32] = 0.f;
    }
    int widx = blockIdx.x * 4 + (tid >> 8);   // 0..39
    int i = tid & 255;
    int word = iq[widx];
    const float* erow = E + (long)word * H;
    float a0 = b[i], a1 = 0.f, a2 = 0.f, a3 = 0.f;
    #pragma unroll 8
    for (int j = 0; j < H; j += 4) {
        a0 += erow[j + 0] * Wx[(j + 0) * H + i];
        a1 += erow[j + 1] * Wx[(j + 1) * H + i];
        a2 += erow[j + 2] * Wx[(j + 2) * H + i];
        a3 += erow[j + 3] * Wx[(j + 3) * H + i];
    }
    ws[WS_XWB + widx * H + i] = (a0 + a1) + (a2 + a3);
}

// ==== k_rnn: P=16 x R=4 register-cached Wh (unchanged from r13) ====
__global__ __launch_bounds__(1024) void k_rnn(const float* __restrict__ Wh,
                      const int* __restrict__ lwi,
                      const float* __restrict__ U, const float* __restrict__ qn,
                      float* __restrict__ ws) {
    __shared__ __attribute__((aligned(16))) float hbuf[2][320];
    __shared__ __attribute__((aligned(16))) float xwb[QLEN][H];
    __shared__ float Z[NNUM][H];
    __shared__ float lg[10];
    int tid = threadIdx.x;
    int g = tid >> 4;    // 0..63 (outputs i = g*4 + 0..3)
    int p = tid & 15;    // 0..15 (j = p*16 .. p*16+15)
    int pb = p * 20;     // sw(p*16)

    float4 w4[16];
    #pragma unroll
    for (int jj = 0; jj < 16; ++jj)
        w4[jj] = *(const float4*)&Wh[(p * 16 + jj) * H + g * 4];

    {
        const float4* src = (const float4*)&ws[WS_XWB];
        float4* dst = (float4*)&xwb[0][0];
        for (int idx = tid; idx < QLEN * H / 4; idx += 1024) dst[idx] = src[idx];
    }
    if (tid < H) hbuf[0][sw(tid)] = 0.f;
    __syncthreads();

    int lw0 = lwi[0], lw1 = lwi[1], lw2 = lwi[2], lw3 = lwi[3], lw4 = lwi[4];
    int cur = 0;
    for (int t = 0; t < QLEN; ++t) {
        const float* hb = &hbuf[cur][pb];
        float4 h0 = *(const float4*)&hb[0];
        float4 h1 = *(const float4*)&hb[4];
        float4 h2 = *(const float4*)&hb[8];
        float4 h3 = *(const float4*)&hb[12];
        float a0 = 0.f, a1 = 0.f, a2 = 0.f, a3 = 0.f;
        #define RNN_FMA(hv, e, jj) \
            a0 += hv.e * w4[jj].x; a1 += hv.e * w4[jj].y; \
            a2 += hv.e * w4[jj].z; a3 += hv.e * w4[jj].w;
        RNN_FMA(h0, x, 0)  RNN_FMA(h0, y, 1)  RNN_FMA(h0, z, 2)  RNN_FMA(h0, w, 3)
        RNN_FMA(h1, x, 4)  RNN_FMA(h1, y, 5)  RNN_FMA(h1, z, 6)  RNN_FMA(h1, w, 7)
        RNN_FMA(h2, x, 8)  RNN_FMA(h2, y, 9)  RNN_FMA(h2, z, 10) RNN_FMA(h2, w, 11)
        RNN_FMA(h3, x, 12) RNN_FMA(h3, y, 13) RNN_FMA(h3, z, 14) RNN_FMA(h3, w, 15)
        #undef RNN_FMA
        a0 = reduce16(a0); a1 = reduce16(a1); a2 = reduce16(a2); a3 = reduce16(a3);
        if (p < 4) {
            float s = (p == 0) ? a0 : (p == 1) ? a1 : (p == 2) ? a2 : a3;
            int i = g * 4 + p;
            float hn = fast_tanh(xwb[t][i] + s);
            hbuf[cur ^ 1][sw(i)] = hn;
            if (t == lw0) Z[0][i] = hn;
            if (t == lw1) Z[1][i] = hn;
            if (t == lw2) Z[2][i] = hn;
            if (t == lw3) Z[3][i] = hn;
            if (t == lw4) Z[4][i] = hn;
        }
        __syncthreads();
        cur ^= 1;
    }
    if (tid < H) ws[WS_Q + tid] = hbuf[cur][sw(tid)];

    int grp = tid >> 5;
    int lane = tid & 31;
    if (grp < 10) {
        int u = grp / 5, n = grp % 5;
        float s = 0.f;
        #pragma unroll
        for (int k = 0; k < 8; ++k) {
            int j = lane + k * 32;
            s += Z[n][j] * U[u * H + j];
        }
        s += __shfl_xor(s, 1);
        s += __shfl_xor(s, 2);
        s += __shfl_xor(s, 4);
        s += __shfl_xor(s, 8);
        s += __shfl_xor(s, 16);
        if (lane == 0) lg[grp] = s;
    }
    __syncthreads();
    if (tid < 2) {
        float m = -1e30f;
        for (int n = 0; n < 5; ++n) m = fmaxf(m, lg[tid * 5 + n]);
        float e[5], s = 0.f;
        for (int n = 0; n < 5; ++n) { e[n] = expf(lg[tid * 5 + n] - m); s += e[n]; }
        float piv = 0.f;
        for (int n = 0; n < 5; ++n) piv += (e[n] / s) * qn[n];
        ws[WS_PIV + (tid == 0 ? 1 : 0)] = piv;   // PIV[0]=g, PIV[1]=l
    }
}

// ==== k_selF: 12 workers + 72 M-blocks; per-worker SEPARATE flag lines
// (release-store, no RMW) replace the all-to-all ARR counter.
__global__ __launch_bounds__(1024) void k_selF(
        const float* __restrict__ W_op, const float* __restrict__ W_col,
        const float* __restrict__ W_hh, const float* __restrict__ W_hc,
        const float* __restrict__ op_emb, const float* __restrict__ col_emb,
        float* __restrict__ ws) {
    __shared__ __attribute__((aligned(16))) float smem[36864];   // 144 KB union
    const int tid = threadIdx.x;
    const int blk = blockIdx.x;

    if (blk < NW) {
        // ================= selector worker =================
        float* wlds  = smem;             // [64][257]
        float* mlds  = smem + 16448;     // [73][256]
        float* hl    = smem + 35136;     // 320 swz (q then h)
        float* Pl    = smem + 35456;     // 64
        float* uop   = smem + 35520;     // 320 swz
        float* ucol  = smem + 35840;     // 320 swz
        float* vhh   = smem + 36160;     // 256
        float* lgs   = smem + 36416;     // 80
        float* aop_s = smem + 36496;     // 16
        float* acol_s= smem + 36512;     // 64
        const int wb = blk * 64;
        const int r  = tid >> 4;         // 0..63
        const int p  = tid & 15;
        const int pb = p * 20;

        // stage weight slice (no deps); q plain-read (prior launch)
        for (int idx = tid; idx < 64 * 64; idx += 1024) {
            int rr = idx >> 6, j4 = idx & 63;
            int o = wb + rr;
            const float* src = (o < 256) ? &W_op[(long)o * 512 + 256]
                             : (o < 512) ? &W_col[(long)(o - 256) * 512 + 256]
                             : &W_hh[(long)(o - 512) * 256];
            float4 v = *(const float4*)&src[j4 * 4];
            float* d = &wlds[rr * 257 + j4 * 4];
            d[0] = v.x; d[1] = v.y; d[2] = v.z; d[3] = v.w;
        }
        if (tid < 256) hl[sw(tid)] = ws[WS_Q + tid];
        // wait M (same-launch producers), stage M via agent atomic loads
        if (tid == 0) while (flag_acq(&ws[WS_MDONE]) < NMB - 0.5f) __builtin_amdgcn_s_sleep(1);
        __syncthreads();
        for (int idx = tid; idx < 73 * 256; idx += 1024)
            mlds[idx] = aload(&ws[WS_MOP + idx]);
        __syncthreads();
        // P prologue
        {
            int o = wb + r;
            float s = 0.f;
            if (o < 512) {
                const float* row = (o < 256) ? &W_op[(long)o * 512 + p * 16]
                                             : &W_col[(long)(o - 256) * 512 + p * 16];
                float4 r0 = *(const float4*)&row[0];
                float4 r1 = *(const float4*)&row[4];
                float4 r2 = *(const float4*)&row[8];
                float4 r3 = *(const float4*)&row[12];
                const float* qq = &hl[pb];
                s = dot4(r0, *(const float4*)&qq[0]) + dot4(r1, *(const float4*)&qq[4])
                  + dot4(r2, *(const float4*)&qq[8]) + dot4(r3, *(const float4*)&qq[12]);
            }
            s = reduce16(s);
            if (p == 0) Pl[r] = s;
        }
        __syncthreads();
        // u0 publish + own flag = 1 (release)
        if (tid < 64) {
            int o = wb + tid;
            float val = (o < 512) ? fast_tanh(Pl[tid]) : 0.f;
            astore(&ws[WS_UBUF + 0 * 768 + o], val);
        }
        __threadfence();
        __syncthreads();
        if (tid == 0) flag_rel_store(&ws[WS_WFLAG + blk * 32], 1.f);

        for (int t = 0; t < T_STEPS; ++t) {
            // wait: all 12 per-worker flags >= t+1 (parallel pollers)
            if (tid < NW) {
                while (flag_acq(&ws[WS_WFLAG + tid * 32]) < (float)t + 0.5f)
                    __builtin_amdgcn_s_sleep(1);
            }
            __syncthreads();
            if (tid < 256) {
                uop[sw(tid)]  = aload(&ws[WS_UBUF + t * 768 + tid]);
                ucol[sw(tid)] = aload(&ws[WS_UBUF + t * 768 + 256 + tid]);
                vhh[tid]      = aload(&ws[WS_UBUF + t * 768 + 512 + tid]);
            }
            __syncthreads();
            // logits (redundant-complete per worker)
            {
                const float* urow = &ucol[pb];
                float4 u0 = *(const float4*)&urow[0];
                float4 u1 = *(const float4*)&urow[4];
                float4 u2 = *(const float4*)&urow[8];
                float4 u3 = *(const float4*)&urow[12];
                const float* erow = &col_emb[r * 256 + p * 16];
                float4 e0 = *(const float4*)&erow[0];
                float4 e1 = *(const float4*)&erow[4];
                float4 e2 = *(const float4*)&erow[8];
                float4 e3 = *(const float4*)&erow[12];
                float s = dot4(e0, u0) + dot4(e1, u1) + dot4(e2, u2) + dot4(e3, u3);
                s = reduce16(s);
                if (p == 0) lgs[NOPS + r] = s;
                if (r < NOPS) {
                    const float* vrow = &uop[pb];
                    float4 v0 = *(const float4*)&vrow[0];
                    float4 v1 = *(const float4*)&vrow[4];
                    float4 v2 = *(const float4*)&vrow[8];
                    float4 v3 = *(const float4*)&vrow[12];
                    const float* orow = &op_emb[r * 256 + p * 16];
                    float4 f0 = *(const float4*)&orow[0];
                    float4 f1 = *(const float4*)&orow[4];
                    float4 f2 = *(const float4*)&orow[8];
                    float4 f3 = *(const float4*)&orow[12];
                    float so = dot4(f0, v0) + dot4(f1, v1) + dot4(f2, v2) + dot4(f3, v3);
                    so = reduce16(so);
                    if (p == 0) lgs[r] = so;
                }
            }
            __syncthreads();
            // softmaxes (local; worker 0 publishes for k_table)
            if (tid == 0) {
                float m = -1e30f;
                for (int k = 0; k < NOPS; ++k) m = fmaxf(m, lgs[k]);
                float e[NOPS], s = 0.f;
                for (int k = 0; k < NOPS; ++k) { e[k] = expf(lgs[k] - m); s += e[k]; }
                float inv = 1.f / s;
                for (int k = 0; k < NOPS; ++k) {
                    float a = e[k] * inv;
                    aop_s[k] = a;
                    if (blk == 0) ws[WS_AOP + t * 16 + k] = a;
                }
            }
            if (tid >= 64 && tid < 128) {
                int lane = tid - 64;
                float v = lgs[NOPS + lane];
                float m = v;
                for (int off = 1; off < 64; off <<= 1) m = fmaxf(m, __shfl_xor(m, off));
                float e = expf(v - m);
                float s = e;
                for (int off = 1; off < 64; off <<= 1) s += __shfl_xor(s, off);
                float a = __fdividef(e, s);
                acol_s[lane] = a;
                if (blk == 0) ws[WS_ACOL + t * COLSN + lane] = a;
            }
            __syncthreads();
            if (t < T_STEPS - 1) {
                // local h-update
                if (tid < 256) {
                    float s = vhh[tid];
                    #pragma unroll
                    for (int k = 0; k < NOPS; ++k) s += aop_s[k] * mlds[k * 256 + tid];
                    #pragma unroll 8
                    for (int c = 0; c < COLSN; ++c) s += acol_s[c] * mlds[(NOPS + c) * 256 + tid];
                    hl[sw(tid)] = fast_tanh(s);
                }
                __syncthreads();
                // matvec for u[t+1]
                {
                    int o = wb + r;
                    const float* wr = &wlds[r * 257 + p * 16];
                    float4 w0 = *(const float4*)&wr[0];
                    float4 w1 = *(const float4*)&wr[4];
                    float4 w2 = *(const float4*)&wr[8];
                    float4 w3 = *(const float4*)&wr[12];
                    const float* hh = &hl[pb];
                    float s = dot4(w0, *(const float4*)&hh[0]) + dot4(w1, *(const float4*)&hh[4])
                            + dot4(w2, *(const float4*)&hh[8]) + dot4(w3, *(const float4*)&hh[12]);
                    s = reduce16(s);
                    if (p == 0) {
                        float val = (o < 512) ? fast_tanh(Pl[r] + s) : s;
                        astore(&ws[WS_UBUF + (t + 1) * 768 + o], val);
                    }
                }
                __threadfence();
                __syncthreads();
                if (tid == 0) flag_rel_store(&ws[WS_WFLAG + blk * 32], (float)(t + 2));
            }
        }
    } else {
        // ================= M blocks (8 itiles x 9 kgroups) =================
        float* tile = smem;   // [32][268]
        int mb = blk - NW;    // 0..71
        int bi = mb / 9;
        int kg = mb % 9;
        int ibase = bi * 32;
        int coff = (kg == 0) ? 0 : H;
        for (int idx = tid; idx < 32 * 64; idx += 1024) {
            int rr = idx >> 6, c4 = idx & 63;
            float4 v = *(const float4*)&W_hc[(long)(ibase + rr) * 512 + coff + c4 * 4];
            float* d = &tile[rr * 268 + c4 * 4];
            d[0] = v.x; d[1] = v.y; d[2] = v.z; d[3] = v.w;
        }
        __syncthreads();
        int io = tid >> 5;            // 0..31
        int l32 = tid & 31;
        int nk = (kg == 0) ? NOPS : 8;
        for (int kk = 0; kk < nk; ++kk) {
            const float* emb;
            int dst;
            if (kg == 0) { emb = op_emb + kk * H; dst = WS_MOP + kk * H; }
            else { int c = (kg - 1) * 8 + kk; emb = col_emb + c * H; dst = WS_MCOL + c * H; }
            float s = 0.f;
            #pragma unroll
            for (int q8 = 0; q8 < 8; ++q8) {
                int q = (q8 + l32) & 7;
                s += tile[io * 268 + l32 * 8 + q] * emb[l32 * 8 + q];
            }
            s += __shfl_xor(s, 1);
            s += __shfl_xor(s, 2);
            s += __shfl_xor(s, 4);
            s += __shfl_xor(s, 8);
            s += __shfl_xor(s, 16);
            if (l32 == 0) astore(&ws[dst + ibase + io], s);
        }
        __threadfence();
        __syncthreads();
        if (tid == 0) flag_rel_add(&ws[WS_MDONE], 1.f);
    }
}

// ==== k_table: unchanged (r10 known-good) ====
__global__ __launch_bounds__(512) void k_table(const float* __restrict__ table,
                                               float* __restrict__ ws,
                                               float* __restrict__ out) {
    __shared__ __attribute__((aligned(16))) float4 acT4[4][17];
    __shared__ float aop_l[64];
    __shared__ float rs3s[8][16];
    __shared__ float bred[8][8];
    __shared__ int lastblk;
    const int tid = threadIdx.x;
    const int wid = tid >> 6;
    const int lane = tid & 63;
    const int r16 = lane & 15;
    const int q = lane >> 4;

    if (tid < 64) {
        aop_l[tid] = ws[WS_AOP + tid];
        acT4[tid >> 4][tid & 15] = make_float4(
            ws[WS_ACOL + 0 * COLSN + tid], ws[WS_ACOL + 1 * COLSN + tid],
            ws[WS_ACOL + 2 * COLSN + tid], ws[WS_ACOL + 3 * COLSN + tid]);
    }
    __syncthreads();
    const float gp = ws[WS_PIV + 0];
    const float lp = ws[WS_PIV + 1];
    const float ac3 = acT4[q][r16].w;

    float dacc[4] = {0,0,0,0}, cacc[4] = {0,0,0,0};

    for (int tile = blockIdx.x; tile < NTBL_TILES; tile += NTBL_BLOCKS) {
        long wrow = (long)tile * 128 + wid * 16;
        bool active = wrow < ROWSN;

        float cv[4] = {0,0,0,0}, gs[4] = {0,0,0,0}, ls[4] = {0,0,0,0};
        if (active) {
            const float* src = table + (wrow + r16) * COLSN + q * 16;
            float4 x0 = *(const float4*)&src[0];
            float4 x1 = *(const float4*)&src[4];
            float4 x2 = *(const float4*)&src[8];
            float4 x3 = *(const float4*)&src[12];
            float xs[16] = {x0.x,x0.y,x0.z,x0.w, x1.x,x1.y,x1.z,x1.w,
                            x2.x,x2.y,x2.z,x2.w, x3.x,x3.y,x3.z,x3.w};
            #pragma unroll
            for (int jj = 0; jj < 16; ++jj) {
                float x = xs[jj];
                float4 a4 = acT4[q][jj];
                float gt = (x > gp) ? 1.f : 0.f;
                float lt = (x < lp) ? 1.f : 0.f;
                cv[0] += x * a4.x;  cv[1] += x * a4.y;  cv[2] += x * a4.z;  cv[3] += x * a4.w;
                gs[0] += gt * a4.x; gs[1] += gt * a4.y; gs[2] += gt * a4.z; gs[3] += gt * a4.w;
                ls[0] += lt * a4.x; ls[1] += lt * a4.y; ls[2] += lt * a4.z; ls[3] += lt * a4.w;
            }
        }
        #pragma unroll
        for (int k = 0; k < 4; ++k) {
            cv[k] += __shfl_xor(cv[k], 16); cv[k] += __shfl_xor(cv[k], 32);
            gs[k] += __shfl_xor(gs[k], 16); gs[k] += __shfl_xor(gs[k], 32);
            ls[k] += __shfl_xor(ls[k], 16); ls[k] += __shfl_xor(ls[k], 32);
        }

        float prev1 = 1.f, prev2 = 1.f;
        #pragma unroll
        for (int t = 0; t < 4; ++t) {
            if (active) { dacc[t] += prev1 * cv[t]; cacc[t] += prev1; }
            float cg = aop_l[t*16+3], cl = aop_l[t*16+4], cmn = aop_l[t*16+5];
            float cmx = aop_l[t*16+6], co = aop_l[t*16+8];
            float cid = aop_l[t*16+0] + aop_l[t*16+1] + aop_l[t*16+2] + aop_l[t*16+7];
            float rsn = cg * gs[t] + cl * ls[t] + cmn * fminf(prev1, prev2)
                      + cmx * fmaxf(prev1, prev2) + co + cid * prev1;
            prev2 = prev1; prev1 = rsn;
        }
        if (q == 0 && active) rs3s[wid][r16] = prev1 * aop_l[3*16+7];

        if (active) {
            float* dst = out + 1 + wrow * COLSN;
            #pragma unroll 4
            for (int s = 0; s < 16; ++s)
                dst[(long)s * COLSN + lane] = rs3s[wid][s] * ac3;
        }
    }

    float vals[8];
    #pragma unroll
    for (int t = 0; t < 4; ++t) { vals[t] = dacc[t]; vals[4 + t] = cacc[t]; }
    #pragma unroll
    for (int k = 0; k < 8; ++k) vals[k] = reduce16(vals[k]);
    if (lane == 0) {
        #pragma unroll
        for (int k = 0; k < 8; ++k) bred[wid][k] = vals[k];
    }
    __syncthreads();
    if (tid < 8) {
        float s = 0.f;
        #pragma unroll
        for (int w = 0; w < 8; ++w) s += bred[w][tid];
        atomicAdd(&ws[WS_PACC8 + tid], s);
    }
    __syncthreads();

    if (tid == 0) {
        float old = atomicAdd(&ws[WS_TICKET], 1.0f);
        lastblk = ((int)(old + 0.5f) == NTBL_BLOCKS - 1) ? 1 : 0;
    }
    __syncthreads();
    if (lastblk) {
        if (tid < 8) bred[0][tid] = atomicAdd(&ws[WS_PACC8 + tid], 0.f);
        __syncthreads();
        if (tid == 0) {
            float d0 = bred[0][0], d1 = bred[0][1], d2 = bred[0][2], d3 = bred[0][3];
            float c0 = bred[0][4], c1 = bred[0][5], c2 = bred[0][6], c3 = bred[0][7];
            float s0 = aop_l[0]*d0  + aop_l[1]*c0;
            float s1 = aop_l[16]*d1 + aop_l[17]*c1 + aop_l[18]*(0.f - s0);
            float s2 = aop_l[32]*d2 + aop_l[33]*c2 + aop_l[34]*(0.f - s1);
            float s3 = aop_l[48]*d3 + aop_l[49]*c3 + aop_l[50]*(s0 - s2);
            out[0] = s3;
        }
    }
}

extern "C" void kernel_launch(void* const* d_in, const int* in_sizes, int n_in,
                              void* d_out, int out_size, void* d_ws, size_t ws_size,
                              hipStream_t stream) {
    const int*   iq      = (const int*)  d_in[0];
    const float* qn      = (const float*)d_in[1];
    const int*   lwi     = (const int*)  d_in[2];
    const float* table   = (const float*)d_in[3];
    const float* E       = (const float*)d_in[4];
    const float* Wx      = (const float*)d_in[5];
    const float* Wh      = (const float*)d_in[6];
    const float* b       = (const float*)d_in[7];
    const float* W_op    = (const float*)d_in[8];
    const float* op_emb  = (const float*)d_in[9];
    const float* W_col   = (const float*)d_in[10];
    const float* col_emb = (const float*)d_in[11];
    const float* U       = (const float*)d_in[12];
    const float* W_hc    = (const float*)d_in[13];
    const float* W_hh    = (const float*)d_in[14];
    float* out = (float*)d_out;
    float* ws  = (float*)d_ws;

    hipLaunchKernelGGL(k_pre,  dim3(10), dim3(1024), 0, stream, iq, E, Wx, b, ws);
    hipLaunchKernelGGL(k_rnn,  dim3(1), dim3(1024), 0, stream, Wh, lwi, U, qn, ws);
    hipLaunchKernelGGL(k_selF, dim3(NSELF), dim3(1024), 0, stream,
                       W_op, W_col, W_hh, W_hc, op_emb, col_emb, ws);
    hipLaunchKernelGGL(k_table, dim3(NTBL_BLOCKS), dim3(512), 0, stream,
                       table, ws, out);
}

// Round 15
// 147.071 us; speedup vs baseline: 1.1764x; 1.1764x over previous
//
#include <hip/hip_runtime.h>
#include <math.h>

#define H 256
#define COLSN 64
#define ROWSN 200000
#define T_STEPS 4
#define QLEN 40
#define NNUM 5
#define NOPS 9

// workspace float offsets
#define WS_XWB    0          // 40*256 (k_pre -> k_rnn)
#define WS_Q      10240      // 256
#define WS_AOP    10496      // 4*16
#define WS_ACOL   10560      // 4*64
#define WS_PIV    10816      // [0]=g [1]=l
#define WS_TICKET 10818
#define WS_PACC8  10824      // 8
#define WS_MOP    11104      // 9*256 (MOP+MCOL contiguous 73*256)
#define WS_MCOL   13408      // 64*256

#define NTBL_TILES  1563
#define NTBL_BLOCKS 782
#define NXW 10               // xw blocks
#define NMB 72               // M blocks

template<int CTRL>
__device__ __forceinline__ float dpp_add(float x) {
    int xi = __float_as_int(x);
    int yi = __builtin_amdgcn_update_dpp(0, xi, CTRL, 0xF, 0xF, true);
    return x + __int_as_float(yi);
}
#define DPP_XOR1 0xB1
#define DPP_XOR2 0x4E
#define DPP_HMIR 0x141
#define DPP_MIR  0x140

__device__ __forceinline__ float reduce16(float v) {
    v = dpp_add<DPP_XOR1>(v);
    v = dpp_add<DPP_XOR2>(v);
    v = dpp_add<DPP_HMIR>(v);
    v = dpp_add<DPP_MIR>(v);
    return v;
}

__device__ __forceinline__ float fast_tanh(float x) {
    float cx = fminf(15.f, fmaxf(-15.f, x));
    float e = __expf(2.f * cx);
    return __fdividef(e - 1.f, e + 1.f);
}

__device__ __forceinline__ float dot4(float4 a, float4 b) {
    return a.x * b.x + a.y * b.y + a.z * b.z + a.w * b.w;
}

// LDS swizzle: +4 floats pad per 16
__device__ __forceinline__ int sw(int i) { return i + ((i >> 4) << 2); }

// ==== k_pre: blocks 0..9 -> X@Wx+b (4 words each); blocks 10..81 -> M ====
__global__ __launch_bounds__(1024) void k_pre(const int* __restrict__ iq,
        const float* __restrict__ E, const float* __restrict__ Wx,
        const float* __restrict__ b, const float* __restrict__ W_hc,
        const float* __restrict__ op_emb, const float* __restrict__ col_emb,
        float* __restrict__ ws) {
    int blk = blockIdx.x;
    int tid = threadIdx.x;
    if (blk < NXW) {
        if (blk == 0 && tid < 16) ws[WS_TICKET + tid] = 0.f;   // ticket + PACC8
        int widx = blk * 4 + (tid >> 8);   // 0..39
        int i = tid & 255;
        int word = iq[widx];
        const float* erow = E + (long)word * H;
        float a0 = b[i], a1 = 0.f, a2 = 0.f, a3 = 0.f;
        #pragma unroll 8
        for (int j = 0; j < H; j += 4) {
            a0 += erow[j + 0] * Wx[(j + 0) * H + i];
            a1 += erow[j + 1] * Wx[(j + 1) * H + i];
            a2 += erow[j + 2] * Wx[(j + 2) * H + i];
            a3 += erow[j + 3] * Wx[(j + 3) * H + i];
        }
        ws[WS_XWB + widx * H + i] = (a0 + a1) + (a2 + a3);
    } else {
        // M_op[k][i] = op_emb[k].W_hc[i][0:256] ; M_col[c][i] = col_emb[c].W_hc[i][256:512]
        __shared__ __attribute__((aligned(16))) float tile[32][268];
        int mb = blk - NXW;           // 0..71
        int bi = mb / 9;
        int kg = mb % 9;
        int ibase = bi * 32;
        int coff = (kg == 0) ? 0 : H;
        for (int idx = tid; idx < 32 * 64; idx += 1024) {
            int rr = idx >> 6, c4 = idx & 63;
            float4 v = *(const float4*)&W_hc[(long)(ibase + rr) * 512 + coff + c4 * 4];
            float* d = &tile[rr][c4 * 4];
            d[0] = v.x; d[1] = v.y; d[2] = v.z; d[3] = v.w;
        }
        __syncthreads();
        int io = tid >> 5;            // 0..31
        int l32 = tid & 31;
        int nk = (kg == 0) ? NOPS : 8;
        for (int kk = 0; kk < nk; ++kk) {
            const float* emb;
            int dst;
            if (kg == 0) { emb = op_emb + kk * H; dst = WS_MOP + kk * H; }
            else { int c = (kg - 1) * 8 + kk; emb = col_emb + c * H; dst = WS_MCOL + c * H; }
            float s = 0.f;
            #pragma unroll
            for (int q8 = 0; q8 < 8; ++q8) {
                int q = (q8 + l32) & 7;
                s += tile[io][l32 * 8 + q] * emb[l32 * 8 + q];
            }
            s += __shfl_xor(s, 1);
            s += __shfl_xor(s, 2);
            s += __shfl_xor(s, 4);
            s += __shfl_xor(s, 8);
            s += __shfl_xor(s, 16);
            if (l32 == 0) ws[dst + ibase + io] = s;
        }
    }
}

// ==== k_rnn: r10-proven P=8 x R=2 (42 us, VGPR ~80) ====
__global__ __launch_bounds__(1024) void k_rnn(const float* __restrict__ Wh,
                      const int* __restrict__ lwi,
                      const float* __restrict__ U, const float* __restrict__ qn,
                      float* __restrict__ ws) {
    __shared__ __attribute__((aligned(16))) float hbuf[2][288];
    __shared__ __attribute__((aligned(16))) float xwb[QLEN][H];
    __shared__ float Z[NNUM][H];
    __shared__ float lg[10];
    int tid = threadIdx.x;
    int g = tid >> 3;
    int p = tid & 7;

    float2 w2[32];
    #pragma unroll
    for (int jj = 0; jj < 32; ++jj)
        w2[jj] = *(const float2*)&Wh[(p * 32 + jj) * H + g * 2];

    {
        const float4* src = (const float4*)&ws[WS_XWB];
        float4* dst = (float4*)&xwb[0][0];
        for (int idx = tid; idx < QLEN * H / 4; idx += 1024) dst[idx] = src[idx];
    }
    if (tid < H) hbuf[0][tid + ((tid >> 5) << 2)] = 0.f;
    __syncthreads();

    int lw0 = lwi[0], lw1 = lwi[1], lw2 = lwi[2], lw3 = lwi[3], lw4 = lwi[4];
    int cur = 0;
    for (int t = 0; t < QLEN; ++t) {
        const float4* hv = (const float4*)&hbuf[cur][p * 36];
        float a0 = 0.f, a1 = 0.f;
        #pragma unroll
        for (int q4 = 0; q4 < 8; ++q4) {
            float4 h4 = hv[q4];
            float2 wa = w2[q4 * 4 + 0];
            float2 wb = w2[q4 * 4 + 1];
            float2 wc = w2[q4 * 4 + 2];
            float2 wd = w2[q4 * 4 + 3];
            a0 += h4.x * wa.x; a1 += h4.x * wa.y;
            a0 += h4.y * wb.x; a1 += h4.y * wb.y;
            a0 += h4.z * wc.x; a1 += h4.z * wc.y;
            a0 += h4.w * wd.x; a1 += h4.w * wd.y;
        }
        a0 = dpp_add<DPP_XOR1>(a0); a0 = dpp_add<DPP_XOR2>(a0); a0 = dpp_add<DPP_HMIR>(a0);
        a1 = dpp_add<DPP_XOR1>(a1); a1 = dpp_add<DPP_XOR2>(a1); a1 = dpp_add<DPP_HMIR>(a1);
        if (p < 2) {
            float s = (p == 0) ? a0 : a1;
            int i = g * 2 + p;
            float hn = fast_tanh(xwb[t][i] + s);
            hbuf[cur ^ 1][i + ((i >> 5) << 2)] = hn;
            if (t == lw0) Z[0][i] = hn;
            if (t == lw1) Z[1][i] = hn;
            if (t == lw2) Z[2][i] = hn;
            if (t == lw3) Z[3][i] = hn;
            if (t == lw4) Z[4][i] = hn;
        }
        __syncthreads();
        cur ^= 1;
    }
    if (tid < H) ws[WS_Q + tid] = hbuf[cur][tid + ((tid >> 5) << 2)];

    int grp = tid >> 5;
    int lane = tid & 31;
    if (grp < 10) {
        int u = grp / 5, n = grp % 5;
        float s = 0.f;
        #pragma unroll
        for (int k = 0; k < 8; ++k) {
            int j = lane + k * 32;
            s += Z[n][j] * U[u * H + j];
        }
        s += __shfl_xor(s, 1);
        s += __shfl_xor(s, 2);
        s += __shfl_xor(s, 4);
        s += __shfl_xor(s, 8);
        s += __shfl_xor(s, 16);
        if (lane == 0) lg[grp] = s;
    }
    __syncthreads();
    if (tid < 2) {
        float m = -1e30f;
        for (int n = 0; n < 5; ++n) m = fmaxf(m, lg[tid * 5 + n]);
        float e[5], s = 0.f;
        for (int n = 0; n < 5; ++n) { e[n] = expf(lg[tid * 5 + n] - m); s += e[n]; }
        float piv = 0.f;
        for (int n = 0; n < 5; ++n) piv += (e[n] / s) * qn[n];
        ws[WS_PIV + (tid == 0 ? 1 : 0)] = piv;   // PIV[0]=g, PIV[1]=l
    }
}

// ==== k_sel2: ONE block, 1024 threads. No register caching, no cross-block
// sync — weights streamed from L2 each step; M + all state in LDS.
__global__ __launch_bounds__(1024) void k_sel2(
        const float* __restrict__ W_op, const float* __restrict__ W_col,
        const float* __restrict__ W_hh, const float* __restrict__ op_emb,
        const float* __restrict__ col_emb, float* __restrict__ ws) {
    __shared__ float mlds[73 * 256];     // 73 KB (rows 0-8 op, 9-72 col)
    __shared__ __attribute__((aligned(16))) float hl[320];
    __shared__ __attribute__((aligned(16))) float uop[320];
    __shared__ __attribute__((aligned(16))) float ucol[320];
    __shared__ float vhh[256];
    __shared__ float Pl[512];
    __shared__ float lgs[80];
    __shared__ float aop_s[16], acol_s[64];
    const int tid = threadIdx.x;
    const int r  = tid >> 4;     // 0..63
    const int p  = tid & 15;
    const int pb = p * 20;

    for (int idx = tid; idx < 73 * 256; idx += 1024) mlds[idx] = ws[WS_MOP + idx];
    if (tid < 256) hl[sw(tid)] = ws[WS_Q + tid];
    __syncthreads();

    // prologue: P = W[:, :256] @ q  (512 rows, 8 strips)
    {
        float4 q0 = *(const float4*)&hl[pb + 0];
        float4 q1 = *(const float4*)&hl[pb + 4];
        float4 q2 = *(const float4*)&hl[pb + 8];
        float4 q3 = *(const float4*)&hl[pb + 12];
        #pragma unroll 2
        for (int m = 0; m < 8; ++m) {
            int o = m * 64 + r;
            const float* row = (o < 256) ? &W_op[(long)o * 512 + p * 16]
                                         : &W_col[(long)(o - 256) * 512 + p * 16];
            float4 r0 = *(const float4*)&row[0];
            float4 r1 = *(const float4*)&row[4];
            float4 r2 = *(const float4*)&row[8];
            float4 r3 = *(const float4*)&row[12];
            float s = dot4(r0, q0) + dot4(r1, q1) + dot4(r2, q2) + dot4(r3, q3);
            s = reduce16(s);
            if (p == 0) Pl[o] = s;
        }
    }
    __syncthreads();
    // t=0 state: h_hist = 0 -> u = tanh(P), vhh = 0
    if (tid < 256) {
        uop[sw(tid)]  = fast_tanh(Pl[tid]);
        ucol[sw(tid)] = fast_tanh(Pl[256 + tid]);
        vhh[tid] = 0.f;
    }
    __syncthreads();

    for (int t = 0; t < T_STEPS; ++t) {
        // logits: col o=r (all 64 groups); op o=r for r<9
        {
            const float* urow = &ucol[pb];
            float4 u0 = *(const float4*)&urow[0];
            float4 u1 = *(const float4*)&urow[4];
            float4 u2 = *(const float4*)&urow[8];
            float4 u3 = *(const float4*)&urow[12];
            const float* erow = &col_emb[r * 256 + p * 16];
            float4 e0 = *(const float4*)&erow[0];
            float4 e1 = *(const float4*)&erow[4];
            float4 e2 = *(const float4*)&erow[8];
            float4 e3 = *(const float4*)&erow[12];
            float s = dot4(e0, u0) + dot4(e1, u1) + dot4(e2, u2) + dot4(e3, u3);
            s = reduce16(s);
            if (p == 0) lgs[NOPS + r] = s;
            if (r < NOPS) {
                const float* vrow = &uop[pb];
                float4 v0 = *(const float4*)&vrow[0];
                float4 v1 = *(const float4*)&vrow[4];
                float4 v2 = *(const float4*)&vrow[8];
                float4 v3 = *(const float4*)&vrow[12];
                const float* orow = &op_emb[r * 256 + p * 16];
                float4 f0 = *(const float4*)&orow[0];
                float4 f1 = *(const float4*)&orow[4];
                float4 f2 = *(const float4*)&orow[8];
                float4 f3 = *(const float4*)&orow[12];
                float so = dot4(f0, v0) + dot4(f1, v1) + dot4(f2, v2) + dot4(f3, v3);
                so = reduce16(so);
                if (p == 0) lgs[r] = so;
            }
        }
        __syncthreads();
        // softmaxes
        if (tid == 0) {
            float m = -1e30f;
            for (int k = 0; k < NOPS; ++k) m = fmaxf(m, lgs[k]);
            float e[NOPS], s = 0.f;
            for (int k = 0; k < NOPS; ++k) { e[k] = expf(lgs[k] - m); s += e[k]; }
            float inv = 1.f / s;
            for (int k = 0; k < NOPS; ++k) {
                float a = e[k] * inv;
                aop_s[k] = a;
                ws[WS_AOP + t * 16 + k] = a;
            }
        }
        if (tid >= 64 && tid < 128) {
            int lane = tid - 64;
            float v = lgs[NOPS + lane];
            float m = v;
            for (int off = 1; off < 64; off <<= 1) m = fmaxf(m, __shfl_xor(m, off));
            float e = expf(v - m);
            float s = e;
            for (int off = 1; off < 64; off <<= 1) s += __shfl_xor(s, off);
            float a = __fdividef(e, s);
            acol_s[lane] = a;
            ws[WS_ACOL + t * COLSN + lane] = a;
        }
        __syncthreads();
        if (t < T_STEPS - 1) {
            // h-update from M (LDS): h = tanh(vhh + M_op^T a_op + M_col^T a_col)
            if (tid < 256) {
                float s = vhh[tid];
                #pragma unroll
                for (int k = 0; k < NOPS; ++k) s += aop_s[k] * mlds[k * 256 + tid];
                #pragma unroll 8
                for (int c = 0; c < COLSN; ++c) s += acol_s[c] * mlds[(NOPS + c) * 256 + tid];
                hl[sw(tid)] = fast_tanh(s);
            }
            __syncthreads();
            // stage A for t+1: stream 768 rows (12 strips of 64)
            {
                float4 h0 = *(const float4*)&hl[pb + 0];
                float4 h1 = *(const float4*)&hl[pb + 4];
                float4 h2 = *(const float4*)&hl[pb + 8];
                float4 h3 = *(const float4*)&hl[pb + 12];
                #pragma unroll 2
                for (int m = 0; m < 12; ++m) {
                    int o = m * 64 + r;
                    const float* row;
                    if (o < 256)      row = &W_op[(long)o * 512 + 256 + p * 16];
                    else if (o < 512) row = &W_col[(long)(o - 256) * 512 + 256 + p * 16];
                    else              row = &W_hh[(long)(o - 512) * 256 + p * 16];
                    float4 r0 = *(const float4*)&row[0];
                    float4 r1 = *(const float4*)&row[4];
                    float4 r2 = *(const float4*)&row[8];
                    float4 r3 = *(const float4*)&row[12];
                    float s = dot4(r0, h0) + dot4(r1, h1) + dot4(r2, h2) + dot4(r3, h3);
                    s = reduce16(s);
                    if (p == 0) {
                        if (o < 256)      uop[sw(o)] = fast_tanh(Pl[o] + s);
                        else if (o < 512) ucol[sw(o - 256)] = fast_tanh(Pl[o] + s);
                        else              vhh[o - 512] = s;
                    }
                }
            }
            __syncthreads();
        }
    }
}

// ==== k_table: unchanged (r10 known-good) ====
__global__ __launch_bounds__(512) void k_table(const float* __restrict__ table,
                                               float* __restrict__ ws,
                                               float* __restrict__ out) {
    __shared__ __attribute__((aligned(16))) float4 acT4[4][17];
    __shared__ float aop_l[64];
    __shared__ float rs3s[8][16];
    __shared__ float bred[8][8];
    __shared__ int lastblk;
    const int tid = threadIdx.x;
    const int wid = tid >> 6;
    const int lane = tid & 63;
    const int r16 = lane & 15;
    const int q = lane >> 4;

    if (tid < 64) {
        aop_l[tid] = ws[WS_AOP + tid];
        acT4[tid >> 4][tid & 15] = make_float4(
            ws[WS_ACOL + 0 * COLSN + tid], ws[WS_ACOL + 1 * COLSN + tid],
            ws[WS_ACOL + 2 * COLSN + tid], ws[WS_ACOL + 3 * COLSN + tid]);
    }
    __syncthreads();
    const float gp = ws[WS_PIV + 0];
    const float lp = ws[WS_PIV + 1];
    const float ac3 = acT4[q][r16].w;

    float dacc[4] = {0,0,0,0}, cacc[4] = {0,0,0,0};

    for (int tile = blockIdx.x; tile < NTBL_TILES; tile += NTBL_BLOCKS) {
        long wrow = (long)tile * 128 + wid * 16;
        bool active = wrow < ROWSN;

        float cv[4] = {0,0,0,0}, gs[4] = {0,0,0,0}, ls[4] = {0,0,0,0};
        if (active) {
            const float* src = table + (wrow + r16) * COLSN + q * 16;
            float4 x0 = *(const float4*)&src[0];
            float4 x1 = *(const float4*)&src[4];
            float4 x2 = *(const float4*)&src[8];
            float4 x3 = *(const float4*)&src[12];
            float xs[16] = {x0.x,x0.y,x0.z,x0.w, x1.x,x1.y,x1.z,x1.w,
                            x2.x,x2.y,x2.z,x2.w, x3.x,x3.y,x3.z,x3.w};
            #pragma unroll
            for (int jj = 0; jj < 16; ++jj) {
                float x = xs[jj];
                float4 a4 = acT4[q][jj];
                float gt = (x > gp) ? 1.f : 0.f;
                float lt = (x < lp) ? 1.f : 0.f;
                cv[0] += x * a4.x;  cv[1] += x * a4.y;  cv[2] += x * a4.z;  cv[3] += x * a4.w;
                gs[0] += gt * a4.x; gs[1] += gt * a4.y; gs[2] += gt * a4.z; gs[3] += gt * a4.w;
                ls[0] += lt * a4.x; ls[1] += lt * a4.y; ls[2] += lt * a4.z; ls[3] += lt * a4.w;
            }
        }
        #pragma unroll
        for (int k = 0; k < 4; ++k) {
            cv[k] += __shfl_xor(cv[k], 16); cv[k] += __shfl_xor(cv[k], 32);
            gs[k] += __shfl_xor(gs[k], 16); gs[k] += __shfl_xor(gs[k], 32);
            ls[k] += __shfl_xor(ls[k], 16); ls[k] += __shfl_xor(ls[k], 32);
        }

        float prev1 = 1.f, prev2 = 1.f;
        #pragma unroll
        for (int t = 0; t < 4; ++t) {
            if (active) { dacc[t] += prev1 * cv[t]; cacc[t] += prev1; }
            float cg = aop_l[t*16+3], cl = aop_l[t*16+4], cmn = aop_l[t*16+5];
            float cmx = aop_l[t*16+6], co = aop_l[t*16+8];
            float cid = aop_l[t*16+0] + aop_l[t*16+1] + aop_l[t*16+2] + aop_l[t*16+7];
            float rsn = cg * gs[t] + cl * ls[t] + cmn * fminf(prev1, prev2)
                      + cmx * fmaxf(prev1, prev2) + co + cid * prev1;
            prev2 = prev1; prev1 = rsn;
        }
        if (q == 0 && active) rs3s[wid][r16] = prev1 * aop_l[3*16+7];

        if (active) {
            float* dst = out + 1 + wrow * COLSN;
            #pragma unroll 4
            for (int s = 0; s < 16; ++s)
                dst[(long)s * COLSN + lane] = rs3s[wid][s] * ac3;
        }
    }

    float vals[8];
    #pragma unroll
    for (int t = 0; t < 4; ++t) { vals[t] = dacc[t]; vals[4 + t] = cacc[t]; }
    #pragma unroll
    for (int k = 0; k < 8; ++k) vals[k] = reduce16(vals[k]);
    if (lane == 0) {
        #pragma unroll
        for (int k = 0; k < 8; ++k) bred[wid][k] = vals[k];
    }
    __syncthreads();
    if (tid < 8) {
        float s = 0.f;
        #pragma unroll
        for (int w = 0; w < 8; ++w) s += bred[w][tid];
        atomicAdd(&ws[WS_PACC8 + tid], s);
    }
    __syncthreads();

    if (tid == 0) {
        float old = atomicAdd(&ws[WS_TICKET], 1.0f);
        lastblk = ((int)(old + 0.5f) == NTBL_BLOCKS - 1) ? 1 : 0;
    }
    __syncthreads();
    if (lastblk) {
        if (tid < 8) bred[0][tid] = atomicAdd(&ws[WS_PACC8 + tid], 0.f);
        __syncthreads();
        if (tid == 0) {
            float d0 = bred[0][0], d1 = bred[0][1], d2 = bred[0][2], d3 = bred[0][3];
            float c0 = bred[0][4], c1 = bred[0][5], c2 = bred[0][6], c3 = bred[0][7];
            float s0 = aop_l[0]*d0  + aop_l[1]*c0;
            float s1 = aop_l[16]*d1 + aop_l[17]*c1 + aop_l[18]*(0.f - s0);
            float s2 = aop_l[32]*d2 + aop_l[33]*c2 + aop_l[34]*(0.f - s1);
            float s3 = aop_l[48]*d3 + aop_l[49]*c3 + aop_l[50]*(s0 - s2);
            out[0] = s3;
        }
    }
}

extern "C" void kernel_launch(void* const* d_in, const int* in_sizes, int n_in,
                              void* d_out, int out_size, void* d_ws, size_t ws_size,
                              hipStream_t stream) {
    const int*   iq      = (const int*)  d_in[0];
    const float* qn      = (const float*)d_in[1];
    const int*   lwi     = (const int*)  d_in[2];
    const float* table   = (const float*)d_in[3];
    const float* E       = (const float*)d_in[4];
    const float* Wx      = (const float*)d_in[5];
    const float* Wh      = (const float*)d_in[6];
    const float* b       = (const float*)d_in[7];
    const float* W_op    = (const float*)d_in[8];
    const float* op_emb  = (const float*)d_in[9];
    const float* W_col   = (const float*)d_in[10];
    const float* col_emb = (const float*)d_in[11];
    const float* U       = (const float*)d_in[12];
    const float* W_hc    = (const float*)d_in[13];
    const float* W_hh    = (const float*)d_in[14];
    float* out = (float*)d_out;
    float* ws  = (float*)d_ws;

    hipLaunchKernelGGL(k_pre,  dim3(NXW + NMB), dim3(1024), 0, stream,
                       iq, E, Wx, b, W_hc, op_emb, col_emb, ws);
    hipLaunchKernelGGL(k_rnn,  dim3(1), dim3(1024), 0, stream, Wh, lwi, U, qn, ws);
    hipLaunchKernelGGL(k_sel2, dim3(1), dim3(1024), 0, stream,
                       W_op, W_col, W_hh, op_emb, col_emb, ws);
    hipLaunchKernelGGL(k_table, dim3(NTBL_BLOCKS), dim3(512), 0, stream,
                       table, ws, out);
}

// Round 16
// 132.151 us; speedup vs baseline: 1.3092x; 1.1129x over previous
//
#include <hip/hip_runtime.h>
#include <hip/hip_fp16.h>
#include <math.h>

#define H 256
#define COLSN 64
#define ROWSN 200000
#define T_STEPS 4
#define QLEN 40
#define NNUM 5
#define NOPS 9

// workspace float offsets
#define WS_XWB    0          // 40*256 (k_pre -> k_rnn)
#define WS_Q      10240      // 256
#define WS_AOP    10496      // 4*16
#define WS_ACOL   10560      // 4*64
#define WS_PIV    10816      // [0]=g [1]=l
#define WS_TICKET 10818
#define WS_PACC8  10824      // 8
#define WS_MOP    11104      // 9*256 (MOP+MCOL contiguous 73*256)
#define WS_MCOL   13408      // 64*256 (ends 29792)
#define WS_WPK    30720      // fp16 pack: W2 768 rows x 128 u32, then W1 512 x 128
#define WS_END    (30720 + 768*128 + 512*128)   // 194560 floats

#define NTBL_TILES  1563
#define NTBL_BLOCKS 782
#define NXW 10               // xw blocks
#define NMB 72               // M blocks
#define NPK 20               // pack blocks (1280 rows / 64)

template<int CTRL>
__device__ __forceinline__ float dpp_add(float x) {
    int xi = __float_as_int(x);
    int yi = __builtin_amdgcn_update_dpp(0, xi, CTRL, 0xF, 0xF, true);
    return x + __int_as_float(yi);
}
#define DPP_XOR1 0xB1
#define DPP_XOR2 0x4E
#define DPP_HMIR 0x141
#define DPP_MIR  0x140

__device__ __forceinline__ float reduce16(float v) {
    v = dpp_add<DPP_XOR1>(v);
    v = dpp_add<DPP_XOR2>(v);
    v = dpp_add<DPP_HMIR>(v);
    v = dpp_add<DPP_MIR>(v);
    return v;
}

__device__ __forceinline__ float fast_tanh(float x) {
    float cx = fminf(15.f, fmaxf(-15.f, x));
    float e = __expf(2.f * cx);
    return __fdividef(e - 1.f, e + 1.f);
}

__device__ __forceinline__ float dot4(float4 a, float4 b) {
    return a.x * b.x + a.y * b.y + a.z * b.z + a.w * b.w;
}

// LDS swizzle: +4 floats pad per 16
__device__ __forceinline__ int sw(int i) { return i + ((i >> 4) << 2); }

// source row pointer for packed-weight row o (0..1279)
__device__ __forceinline__ const float* wrow_src(int o,
        const float* W_op, const float* W_col, const float* W_hh) {
    if (o < 256)  return &W_op[(long)o * 512 + 256];
    if (o < 512)  return &W_col[(long)(o - 256) * 512 + 256];
    if (o < 768)  return &W_hh[(long)(o - 512) * 256];
    if (o < 1024) return &W_op[(long)(o - 768) * 512];
    return &W_col[(long)(o - 1024) * 512];
}

// ==== k_pre: blocks 0..9 xw; 10..81 M; 82..101 fp16 pack (optional) ====
__global__ __launch_bounds__(1024) void k_pre(const int* __restrict__ iq,
        const float* __restrict__ E, const float* __restrict__ Wx,
        const float* __restrict__ b, const float* __restrict__ W_hc,
        const float* __restrict__ op_emb, const float* __restrict__ col_emb,
        const float* __restrict__ W_op, const float* __restrict__ W_col,
        const float* __restrict__ W_hh, float* __restrict__ ws) {
    int blk = blockIdx.x;
    int tid = threadIdx.x;
    if (blk < NXW) {
        if (blk == 0 && tid < 16) ws[WS_TICKET + tid] = 0.f;   // ticket + PACC8
        int widx = blk * 4 + (tid >> 8);   // 0..39
        int i = tid & 255;
        int word = iq[widx];
        const float* erow = E + (long)word * H;
        float a0 = b[i], a1 = 0.f, a2 = 0.f, a3 = 0.f;
        #pragma unroll 8
        for (int j = 0; j < H; j += 4) {
            a0 += erow[j + 0] * Wx[(j + 0) * H + i];
            a1 += erow[j + 1] * Wx[(j + 1) * H + i];
            a2 += erow[j + 2] * Wx[(j + 2) * H + i];
            a3 += erow[j + 3] * Wx[(j + 3) * H + i];
        }
        ws[WS_XWB + widx * H + i] = (a0 + a1) + (a2 + a3);
    } else if (blk < NXW + NMB) {
        __shared__ __attribute__((aligned(16))) float tile[32][268];
        int mb = blk - NXW;           // 0..71
        int bi = mb / 9;
        int kg = mb % 9;
        int ibase = bi * 32;
        int coff = (kg == 0) ? 0 : H;
        for (int idx = tid; idx < 32 * 64; idx += 1024) {
            int rr = idx >> 6, c4 = idx & 63;
            float4 v = *(const float4*)&W_hc[(long)(ibase + rr) * 512 + coff + c4 * 4];
            float* d = &tile[rr][c4 * 4];
            d[0] = v.x; d[1] = v.y; d[2] = v.z; d[3] = v.w;
        }
        __syncthreads();
        int io = tid >> 5;            // 0..31
        int l32 = tid & 31;
        int nk = (kg == 0) ? NOPS : 8;
        for (int kk = 0; kk < nk; ++kk) {
            const float* emb;
            int dst;
            if (kg == 0) { emb = op_emb + kk * H; dst = WS_MOP + kk * H; }
            else { int c = (kg - 1) * 8 + kk; emb = col_emb + c * H; dst = WS_MCOL + c * H; }
            float s = 0.f;
            #pragma unroll
            for (int q8 = 0; q8 < 8; ++q8) {
                int q = (q8 + l32) & 7;
                s += tile[io][l32 * 8 + q] * emb[l32 * 8 + q];
            }
            s += __shfl_xor(s, 1);
            s += __shfl_xor(s, 2);
            s += __shfl_xor(s, 4);
            s += __shfl_xor(s, 8);
            s += __shfl_xor(s, 16);
            if (l32 == 0) ws[dst + ibase + io] = s;
        }
    } else {
        // fp16 pack: 64 rows x 256 cols per block
        int pb2 = blk - NXW - NMB;    // 0..19
        int wb = pb2 * 64;
        __half2* wpk = (__half2*)(ws + WS_WPK);
        for (int idx = tid; idx < 64 * 128; idx += 1024) {
            int rr = idx >> 7, j2 = idx & 127;
            int o = wb + rr;
            const float* src = wrow_src(o, W_op, W_col, W_hh);
            float2 v = *(const float2*)&src[j2 * 2];
            wpk[(long)o * 128 + j2] = __floats2half2_rn(v.x, v.y);
        }
    }
}

// ==== k_rnn: r10-proven P=8 x R=2 (42 us) ====
__global__ __launch_bounds__(1024) void k_rnn(const float* __restrict__ Wh,
                      const int* __restrict__ lwi,
                      const float* __restrict__ U, const float* __restrict__ qn,
                      float* __restrict__ ws) {
    __shared__ __attribute__((aligned(16))) float hbuf[2][288];
    __shared__ __attribute__((aligned(16))) float xwb[QLEN][H];
    __shared__ float Z[NNUM][H];
    __shared__ float lg[10];
    int tid = threadIdx.x;
    int g = tid >> 3;
    int p = tid & 7;

    float2 w2[32];
    #pragma unroll
    for (int jj = 0; jj < 32; ++jj)
        w2[jj] = *(const float2*)&Wh[(p * 32 + jj) * H + g * 2];

    {
        const float4* src = (const float4*)&ws[WS_XWB];
        float4* dst = (float4*)&xwb[0][0];
        for (int idx = tid; idx < QLEN * H / 4; idx += 1024) dst[idx] = src[idx];
    }
    if (tid < H) hbuf[0][tid + ((tid >> 5) << 2)] = 0.f;
    __syncthreads();

    int lw0 = lwi[0], lw1 = lwi[1], lw2 = lwi[2], lw3 = lwi[3], lw4 = lwi[4];
    int cur = 0;
    for (int t = 0; t < QLEN; ++t) {
        const float4* hv = (const float4*)&hbuf[cur][p * 36];
        float a0 = 0.f, a1 = 0.f;
        #pragma unroll
        for (int q4 = 0; q4 < 8; ++q4) {
            float4 h4 = hv[q4];
            float2 wa = w2[q4 * 4 + 0];
            float2 wb = w2[q4 * 4 + 1];
            float2 wc = w2[q4 * 4 + 2];
            float2 wd = w2[q4 * 4 + 3];
            a0 += h4.x * wa.x; a1 += h4.x * wa.y;
            a0 += h4.y * wb.x; a1 += h4.y * wb.y;
            a0 += h4.z * wc.x; a1 += h4.z * wc.y;
            a0 += h4.w * wd.x; a1 += h4.w * wd.y;
        }
        a0 = dpp_add<DPP_XOR1>(a0); a0 = dpp_add<DPP_XOR2>(a0); a0 = dpp_add<DPP_HMIR>(a0);
        a1 = dpp_add<DPP_XOR1>(a1); a1 = dpp_add<DPP_XOR2>(a1); a1 = dpp_add<DPP_HMIR>(a1);
        if (p < 2) {
            float s = (p == 0) ? a0 : a1;
            int i = g * 2 + p;
            float hn = fast_tanh(xwb[t][i] + s);
            hbuf[cur ^ 1][i + ((i >> 5) << 2)] = hn;
            if (t == lw0) Z[0][i] = hn;
            if (t == lw1) Z[1][i] = hn;
            if (t == lw2) Z[2][i] = hn;
            if (t == lw3) Z[3][i] = hn;
            if (t == lw4) Z[4][i] = hn;
        }
        __syncthreads();
        cur ^= 1;
    }
    if (tid < H) ws[WS_Q + tid] = hbuf[cur][tid + ((tid >> 5) << 2)];

    int grp = tid >> 5;
    int lane = tid & 31;
    if (grp < 10) {
        int u = grp / 5, n = grp % 5;
        float s = 0.f;
        #pragma unroll
        for (int k = 0; k < 8; ++k) {
            int j = lane + k * 32;
            s += Z[n][j] * U[u * H + j];
        }
        s += __shfl_xor(s, 1);
        s += __shfl_xor(s, 2);
        s += __shfl_xor(s, 4);
        s += __shfl_xor(s, 8);
        s += __shfl_xor(s, 16);
        if (lane == 0) lg[grp] = s;
    }
    __syncthreads();
    if (tid < 2) {
        float m = -1e30f;
        for (int n = 0; n < 5; ++n) m = fmaxf(m, lg[tid * 5 + n]);
        float e[5], s = 0.f;
        for (int n = 0; n < 5; ++n) { e[n] = expf(lg[tid * 5 + n] - m); s += e[n]; }
        float piv = 0.f;
        for (int n = 0; n < 5; ++n) piv += (e[n] / s) * qn[n];
        ws[WS_PIV + (tid == 0 ? 1 : 0)] = piv;   // PIV[0]=g, PIV[1]=l
    }
}

// ==== shared selector body (templated on packed-vs-fp32 streaming) ====
template<bool PACKED>
__device__ __forceinline__ void sel_body(
        const float* __restrict__ W_op, const float* __restrict__ W_col,
        const float* __restrict__ W_hh, const float* __restrict__ op_emb,
        const float* __restrict__ col_emb, float* __restrict__ ws) {
    __shared__ float mlds[73 * 256];     // 73 KB
    __shared__ __attribute__((aligned(16))) float hl[320];
    __shared__ __attribute__((aligned(16))) float uop[320];
    __shared__ __attribute__((aligned(16))) float ucol[320];
    __shared__ float vhh[256];
    __shared__ float Pl[512];
    __shared__ float lgs[80];
    __shared__ float aop_s[16], acol_s[64];
    const int tid = threadIdx.x;
    const int r  = tid >> 4;     // 0..63
    const int p  = tid & 15;
    const int pb = p * 20;
    const __half2* wpk = (const __half2*)(ws + WS_WPK);

    for (int idx = tid; idx < 73 * 256; idx += 1024) mlds[idx] = ws[WS_MOP + idx];
    if (tid < 256) hl[sw(tid)] = ws[WS_Q + tid];
    __syncthreads();

    // prologue: P = W1 @ q  (512 rows, 8 strips)
    {
        float4 q0 = *(const float4*)&hl[pb + 0];
        float4 q1 = *(const float4*)&hl[pb + 4];
        float4 q2 = *(const float4*)&hl[pb + 8];
        float4 q3 = *(const float4*)&hl[pb + 12];
        float qv[16] = {q0.x,q0.y,q0.z,q0.w, q1.x,q1.y,q1.z,q1.w,
                        q2.x,q2.y,q2.z,q2.w, q3.x,q3.y,q3.z,q3.w};
        #pragma unroll 2
        for (int m = 0; m < 8; ++m) {
            int o = m * 64 + r;
            float s = 0.f;
            if (PACKED) {
                const __half2* row = wpk + (long)(768 + o) * 128 + p * 8;
                #pragma unroll
                for (int jj = 0; jj < 8; ++jj) {
                    float2 w = __half22float2(row[jj]);
                    s += w.x * qv[2 * jj] + w.y * qv[2 * jj + 1];
                }
            } else {
                const float* row = (o < 256) ? &W_op[(long)o * 512 + p * 16]
                                             : &W_col[(long)(o - 256) * 512 + p * 16];
                s = dot4(*(const float4*)&row[0], q0) + dot4(*(const float4*)&row[4], q1)
                  + dot4(*(const float4*)&row[8], q2) + dot4(*(const float4*)&row[12], q3);
            }
            s = reduce16(s);
            if (p == 0) Pl[o] = s;
        }
    }
    __syncthreads();
    if (tid < 256) {
        uop[sw(tid)]  = fast_tanh(Pl[tid]);
        ucol[sw(tid)] = fast_tanh(Pl[256 + tid]);
        vhh[tid] = 0.f;
    }
    __syncthreads();

    for (int t = 0; t < T_STEPS; ++t) {
        // logits
        {
            const float* urow = &ucol[pb];
            float4 u0 = *(const float4*)&urow[0];
            float4 u1 = *(const float4*)&urow[4];
            float4 u2 = *(const float4*)&urow[8];
            float4 u3 = *(const float4*)&urow[12];
            const float* erow = &col_emb[r * 256 + p * 16];
            float s = dot4(*(const float4*)&erow[0], u0) + dot4(*(const float4*)&erow[4], u1)
                    + dot4(*(const float4*)&erow[8], u2) + dot4(*(const float4*)&erow[12], u3);
            s = reduce16(s);
            if (p == 0) lgs[NOPS + r] = s;
            if (r < NOPS) {
                const float* vrow = &uop[pb];
                float4 v0 = *(const float4*)&vrow[0];
                float4 v1 = *(const float4*)&vrow[4];
                float4 v2 = *(const float4*)&vrow[8];
                float4 v3 = *(const float4*)&vrow[12];
                const float* orow = &op_emb[r * 256 + p * 16];
                float so = dot4(*(const float4*)&orow[0], v0) + dot4(*(const float4*)&orow[4], v1)
                         + dot4(*(const float4*)&orow[8], v2) + dot4(*(const float4*)&orow[12], v3);
                so = reduce16(so);
                if (p == 0) lgs[r] = so;
            }
        }
        __syncthreads();
        // softmaxes
        if (tid == 0) {
            float m = -1e30f;
            for (int k = 0; k < NOPS; ++k) m = fmaxf(m, lgs[k]);
            float e[NOPS], s = 0.f;
            for (int k = 0; k < NOPS; ++k) { e[k] = expf(lgs[k] - m); s += e[k]; }
            float inv = 1.f / s;
            for (int k = 0; k < NOPS; ++k) {
                float a = e[k] * inv;
                aop_s[k] = a;
                ws[WS_AOP + t * 16 + k] = a;
            }
        }
        if (tid >= 64 && tid < 128) {
            int lane = tid - 64;
            float v = lgs[NOPS + lane];
            float m = v;
            for (int off = 1; off < 64; off <<= 1) m = fmaxf(m, __shfl_xor(m, off));
            float e = expf(v - m);
            float s = e;
            for (int off = 1; off < 64; off <<= 1) s += __shfl_xor(s, off);
            float a = __fdividef(e, s);
            acol_s[lane] = a;
            ws[WS_ACOL + t * COLSN + lane] = a;
        }
        __syncthreads();
        if (t < T_STEPS - 1) {
            // h-update from M (LDS)
            if (tid < 256) {
                float s = vhh[tid];
                #pragma unroll
                for (int k = 0; k < NOPS; ++k) s += aop_s[k] * mlds[k * 256 + tid];
                #pragma unroll 8
                for (int c = 0; c < COLSN; ++c) s += acol_s[c] * mlds[(NOPS + c) * 256 + tid];
                hl[sw(tid)] = fast_tanh(s);
            }
            __syncthreads();
            // stage A for t+1: 768 rows, 12 strips
            {
                float4 h0 = *(const float4*)&hl[pb + 0];
                float4 h1 = *(const float4*)&hl[pb + 4];
                float4 h2 = *(const float4*)&hl[pb + 8];
                float4 h3 = *(const float4*)&hl[pb + 12];
                float hv2[16] = {h0.x,h0.y,h0.z,h0.w, h1.x,h1.y,h1.z,h1.w,
                                 h2.x,h2.y,h2.z,h2.w, h3.x,h3.y,h3.z,h3.w};
                #pragma unroll 2
                for (int m = 0; m < 12; ++m) {
                    int o = m * 64 + r;
                    float s = 0.f;
                    if (PACKED) {
                        const __half2* row = wpk + (long)o * 128 + p * 8;
                        #pragma unroll
                        for (int jj = 0; jj < 8; ++jj) {
                            float2 w = __half22float2(row[jj]);
                            s += w.x * hv2[2 * jj] + w.y * hv2[2 * jj + 1];
                        }
                    } else {
                        const float* row;
                        if (o < 256)      row = &W_op[(long)o * 512 + 256 + p * 16];
                        else if (o < 512) row = &W_col[(long)(o - 256) * 512 + 256 + p * 16];
                        else              row = &W_hh[(long)(o - 512) * 256 + p * 16];
                        s = dot4(*(const float4*)&row[0], h0) + dot4(*(const float4*)&row[4], h1)
                          + dot4(*(const float4*)&row[8], h2) + dot4(*(const float4*)&row[12], h3);
                    }
                    s = reduce16(s);
                    if (p == 0) {
                        if (o < 256)      uop[sw(o)] = fast_tanh(Pl[o] + s);
                        else if (o < 512) ucol[sw(o - 256)] = fast_tanh(Pl[o] + s);
                        else              vhh[o - 512] = s;
                    }
                }
            }
            __syncthreads();
        }
    }
}

__global__ __launch_bounds__(1024) void k_sel2_f16(
        const float* __restrict__ W_op, const float* __restrict__ W_col,
        const float* __restrict__ W_hh, const float* __restrict__ op_emb,
        const float* __restrict__ col_emb, float* __restrict__ ws) {
    sel_body<true>(W_op, W_col, W_hh, op_emb, col_emb, ws);
}
__global__ __launch_bounds__(1024) void k_sel2_f32(
        const float* __restrict__ W_op, const float* __restrict__ W_col,
        const float* __restrict__ W_hh, const float* __restrict__ op_emb,
        const float* __restrict__ col_emb, float* __restrict__ ws) {
    sel_body<false>(W_op, W_col, W_hh, op_emb, col_emb, ws);
}

// ==== k_table: unchanged (r10 known-good) ====
__global__ __launch_bounds__(512) void k_table(const float* __restrict__ table,
                                               float* __restrict__ ws,
                                               float* __restrict__ out) {
    __shared__ __attribute__((aligned(16))) float4 acT4[4][17];
    __shared__ float aop_l[64];
    __shared__ float rs3s[8][16];
    __shared__ float bred[8][8];
    __shared__ int lastblk;
    const int tid = threadIdx.x;
    const int wid = tid >> 6;
    const int lane = tid & 63;
    const int r16 = lane & 15;
    const int q = lane >> 4;

    if (tid < 64) {
        aop_l[tid] = ws[WS_AOP + tid];
        acT4[tid >> 4][tid & 15] = make_float4(
            ws[WS_ACOL + 0 * COLSN + tid], ws[WS_ACOL + 1 * COLSN + tid],
            ws[WS_ACOL + 2 * COLSN + tid], ws[WS_ACOL + 3 * COLSN + tid]);
    }
    __syncthreads();
    const float gp = ws[WS_PIV + 0];
    const float lp = ws[WS_PIV + 1];
    const float ac3 = acT4[q][r16].w;

    float dacc[4] = {0,0,0,0}, cacc[4] = {0,0,0,0};

    for (int tile = blockIdx.x; tile < NTBL_TILES; tile += NTBL_BLOCKS) {
        long wrow = (long)tile * 128 + wid * 16;
        bool active = wrow < ROWSN;

        float cv[4] = {0,0,0,0}, gs[4] = {0,0,0,0}, ls[4] = {0,0,0,0};
        if (active) {
            const float* src = table + (wrow + r16) * COLSN + q * 16;
            float4 x0 = *(const float4*)&src[0];
            float4 x1 = *(const float4*)&src[4];
            float4 x2 = *(const float4*)&src[8];
            float4 x3 = *(const float4*)&src[12];
            float xs[16] = {x0.x,x0.y,x0.z,x0.w, x1.x,x1.y,x1.z,x1.w,
                            x2.x,x2.y,x2.z,x2.w, x3.x,x3.y,x3.z,x3.w};
            #pragma unroll
            for (int jj = 0; jj < 16; ++jj) {
                float x = xs[jj];
                float4 a4 = acT4[q][jj];
                float gt = (x > gp) ? 1.f : 0.f;
                float lt = (x < lp) ? 1.f : 0.f;
                cv[0] += x * a4.x;  cv[1] += x * a4.y;  cv[2] += x * a4.z;  cv[3] += x * a4.w;
                gs[0] += gt * a4.x; gs[1] += gt * a4.y; gs[2] += gt * a4.z; gs[3] += gt * a4.w;
                ls[0] += lt * a4.x; ls[1] += lt * a4.y; ls[2] += lt * a4.z; ls[3] += lt * a4.w;
            }
        }
        #pragma unroll
        for (int k = 0; k < 4; ++k) {
            cv[k] += __shfl_xor(cv[k], 16); cv[k] += __shfl_xor(cv[k], 32);
            gs[k] += __shfl_xor(gs[k], 16); gs[k] += __shfl_xor(gs[k], 32);
            ls[k] += __shfl_xor(ls[k], 16); ls[k] += __shfl_xor(ls[k], 32);
        }

        float prev1 = 1.f, prev2 = 1.f;
        #pragma unroll
        for (int t = 0; t < 4; ++t) {
            if (active) { dacc[t] += prev1 * cv[t]; cacc[t] += prev1; }
            float cg = aop_l[t*16+3], cl = aop_l[t*16+4], cmn = aop_l[t*16+5];
            float cmx = aop_l[t*16+6], co = aop_l[t*16+8];
            float cid = aop_l[t*16+0] + aop_l[t*16+1] + aop_l[t*16+2] + aop_l[t*16+7];
            float rsn = cg * gs[t] + cl * ls[t] + cmn * fminf(prev1, prev2)
                      + cmx * fmaxf(prev1, prev2) + co + cid * prev1;
            prev2 = prev1; prev1 = rsn;
        }
        if (q == 0 && active) rs3s[wid][r16] = prev1 * aop_l[3*16+7];

        if (active) {
            float* dst = out + 1 + wrow * COLSN;
            #pragma unroll 4
            for (int s = 0; s < 16; ++s)
                dst[(long)s * COLSN + lane] = rs3s[wid][s] * ac3;
        }
    }

    float vals[8];
    #pragma unroll
    for (int t = 0; t < 4; ++t) { vals[t] = dacc[t]; vals[4 + t] = cacc[t]; }
    #pragma unroll
    for (int k = 0; k < 8; ++k) vals[k] = reduce16(vals[k]);
    if (lane == 0) {
        #pragma unroll
        for (int k = 0; k < 8; ++k) bred[wid][k] = vals[k];
    }
    __syncthreads();
    if (tid < 8) {
        float s = 0.f;
        #pragma unroll
        for (int w = 0; w < 8; ++w) s += bred[w][tid];
        atomicAdd(&ws[WS_PACC8 + tid], s);
    }
    __syncthreads();

    if (tid == 0) {
        float old = atomicAdd(&ws[WS_TICKET], 1.0f);
        lastblk = ((int)(old + 0.5f) == NTBL_BLOCKS - 1) ? 1 : 0;
    }
    __syncthreads();
    if (lastblk) {
        if (tid < 8) bred[0][tid] = atomicAdd(&ws[WS_PACC8 + tid], 0.f);
        __syncthreads();
        if (tid == 0) {
            float d0 = bred[0][0], d1 = bred[0][1], d2 = bred[0][2], d3 = bred[0][3];
            float c0 = bred[0][4], c1 = bred[0][5], c2 = bred[0][6], c3 = bred[0][7];
            float s0 = aop_l[0]*d0  + aop_l[1]*c0;
            float s1 = aop_l[16]*d1 + aop_l[17]*c1 + aop_l[18]*(0.f - s0);
            float s2 = aop_l[32]*d2 + aop_l[33]*c2 + aop_l[34]*(0.f - s1);
            float s3 = aop_l[48]*d3 + aop_l[49]*c3 + aop_l[50]*(s0 - s2);
            out[0] = s3;
        }
    }
}

extern "C" void kernel_launch(void* const* d_in, const int* in_sizes, int n_in,
                              void* d_out, int out_size, void* d_ws, size_t ws_size,
                              hipStream_t stream) {
    const int*   iq      = (const int*)  d_in[0];
    const float* qn      = (const float*)d_in[1];
    const int*   lwi     = (const int*)  d_in[2];
    const float* table   = (const float*)d_in[3];
    const float* E       = (const float*)d_in[4];
    const float* Wx      = (const float*)d_in[5];
    const float* Wh      = (const float*)d_in[6];
    const float* b       = (const float*)d_in[7];
    const float* W_op    = (const float*)d_in[8];
    const float* op_emb  = (const float*)d_in[9];
    const float* W_col   = (const float*)d_in[10];
    const float* col_emb = (const float*)d_in[11];
    const float* U       = (const float*)d_in[12];
    const float* W_hc    = (const float*)d_in[13];
    const float* W_hh    = (const float*)d_in[14];
    float* out = (float*)d_out;
    float* ws  = (float*)d_ws;

    const bool packed = ws_size >= (size_t)WS_END * sizeof(float);
    int npre = NXW + NMB + (packed ? NPK : 0);

    hipLaunchKernelGGL(k_pre,  dim3(npre), dim3(1024), 0, stream,
                       iq, E, Wx, b, W_hc, op_emb, col_emb, W_op, W_col, W_hh, ws);
    hipLaunchKernelGGL(k_rnn,  dim3(1), dim3(1024), 0, stream, Wh, lwi, U, qn, ws);
    if (packed)
        hipLaunchKernelGGL(k_sel2_f16, dim3(1), dim3(1024), 0, stream,
                           W_op, W_col, W_hh, op_emb, col_emb, ws);
    else
        hipLaunchKernelGGL(k_sel2_f32, dim3(1), dim3(1024), 0, stream,
                           W_op, W_col, W_hh, op_emb, col_emb, ws);
    hipLaunchKernelGGL(k_table, dim3(NTBL_BLOCKS), dim3(512), 0, stream,
                       table, ws, out);
}

// Round 17
// 132.107 us; speedup vs baseline: 1.3096x; 1.0003x over previous
//
#include <hip/hip_runtime.h>
#include <hip/hip_fp16.h>
#include <math.h>

#define H 256
#define COLSN 64
#define ROWSN 200000
#define T_STEPS 4
#define QLEN 40
#define NNUM 5
#define NOPS 9

// workspace float offsets
#define WS_XWB    0          // 40*256 (k_pre -> k_rnn)
#define WS_Q      10240      // 256
#define WS_AOP    10496      // 4*16
#define WS_ACOL   10560      // 4*64
#define WS_PIV    10816      // [0]=g [1]=l
#define WS_TICKET 10818
#define WS_PACC8  10824      // 8
#define WS_MOP    11104      // 9*256 (MOP+MCOL contiguous 73*256)
#define WS_MCOL   13408      // 64*256 (ends 29792)
#define WS_WPK    30720      // fp16 pack: W2 768 rows x 128 u32, then W1 512 x 128
#define WS_END    (30720 + 768*128 + 512*128)   // 194560 floats

#define NTBL_TILES  1563
#define NTBL_BLOCKS 782
#define NXW 10               // xw blocks
#define NMB 72               // M blocks
#define NPK 20               // pack blocks

template<int CTRL>
__device__ __forceinline__ float dpp_add(float x) {
    int xi = __float_as_int(x);
    int yi = __builtin_amdgcn_update_dpp(0, xi, CTRL, 0xF, 0xF, true);
    return x + __int_as_float(yi);
}
#define DPP_XOR1 0xB1
#define DPP_XOR2 0x4E
#define DPP_HMIR 0x141
#define DPP_MIR  0x140

__device__ __forceinline__ float reduce16(float v) {
    v = dpp_add<DPP_XOR1>(v);
    v = dpp_add<DPP_XOR2>(v);
    v = dpp_add<DPP_HMIR>(v);
    v = dpp_add<DPP_MIR>(v);
    return v;
}

__device__ __forceinline__ float fast_tanh(float x) {
    float cx = fminf(15.f, fmaxf(-15.f, x));
    float e = __expf(2.f * cx);
    return __fdividef(e - 1.f, e + 1.f);
}

__device__ __forceinline__ float dot4(float4 a, float4 b) {
    return a.x * b.x + a.y * b.y + a.z * b.z + a.w * b.w;
}

// LDS swizzle: +4 floats pad per 16
__device__ __forceinline__ int sw(int i) { return i + ((i >> 4) << 2); }

// source row pointer for packed-weight row o (0..1279)
__device__ __forceinline__ const float* wrow_src(int o,
        const float* W_op, const float* W_col, const float* W_hh) {
    if (o < 256)  return &W_op[(long)o * 512 + 256];
    if (o < 512)  return &W_col[(long)(o - 256) * 512 + 256];
    if (o < 768)  return &W_hh[(long)(o - 512) * 256];
    if (o < 1024) return &W_op[(long)(o - 768) * 512];
    return &W_col[(long)(o - 1024) * 512];
}

// ==== k_pre: blocks 0..9 xw; 10..81 M; 82..101 fp16 pack (optional) ====
__global__ __launch_bounds__(1024) void k_pre(const int* __restrict__ iq,
        const float* __restrict__ E, const float* __restrict__ Wx,
        const float* __restrict__ b, const float* __restrict__ W_hc,
        const float* __restrict__ op_emb, const float* __restrict__ col_emb,
        const float* __restrict__ W_op, const float* __restrict__ W_col,
        const float* __restrict__ W_hh, float* __restrict__ ws) {
    int blk = blockIdx.x;
    int tid = threadIdx.x;
    if (blk < NXW) {
        if (blk == 0 && tid < 16) ws[WS_TICKET + tid] = 0.f;   // ticket + PACC8
        int widx = blk * 4 + (tid >> 8);   // 0..39
        int i = tid & 255;
        int word = iq[widx];
        const float* erow = E + (long)word * H;
        float a0 = b[i], a1 = 0.f, a2 = 0.f, a3 = 0.f;
        #pragma unroll 8
        for (int j = 0; j < H; j += 4) {
            a0 += erow[j + 0] * Wx[(j + 0) * H + i];
            a1 += erow[j + 1] * Wx[(j + 1) * H + i];
            a2 += erow[j + 2] * Wx[(j + 2) * H + i];
            a3 += erow[j + 3] * Wx[(j + 3) * H + i];
        }
        ws[WS_XWB + widx * H + i] = (a0 + a1) + (a2 + a3);
    } else if (blk < NXW + NMB) {
        __shared__ __attribute__((aligned(16))) float tile[32][268];
        int mb = blk - NXW;           // 0..71
        int bi = mb / 9;
        int kg = mb % 9;
        int ibase = bi * 32;
        int coff = (kg == 0) ? 0 : H;
        for (int idx = tid; idx < 32 * 64; idx += 1024) {
            int rr = idx >> 6, c4 = idx & 63;
            float4 v = *(const float4*)&W_hc[(long)(ibase + rr) * 512 + coff + c4 * 4];
            float* d = &tile[rr][c4 * 4];
            d[0] = v.x; d[1] = v.y; d[2] = v.z; d[3] = v.w;
        }
        __syncthreads();
        int io = tid >> 5;            // 0..31
        int l32 = tid & 31;
        int nk = (kg == 0) ? NOPS : 8;
        for (int kk = 0; kk < nk; ++kk) {
            const float* emb;
            int dst;
            if (kg == 0) { emb = op_emb + kk * H; dst = WS_MOP + kk * H; }
            else { int c = (kg - 1) * 8 + kk; emb = col_emb + c * H; dst = WS_MCOL + c * H; }
            float s = 0.f;
            #pragma unroll
            for (int q8 = 0; q8 < 8; ++q8) {
                int q = (q8 + l32) & 7;
                s += tile[io][l32 * 8 + q] * emb[l32 * 8 + q];
            }
            s += __shfl_xor(s, 1);
            s += __shfl_xor(s, 2);
            s += __shfl_xor(s, 4);
            s += __shfl_xor(s, 8);
            s += __shfl_xor(s, 16);
            if (l32 == 0) ws[dst + ibase + io] = s;
        }
    } else {
        // fp16 pack: 64 rows x 256 cols per block
        int pb2 = blk - NXW - NMB;    // 0..19
        int wb = pb2 * 64;
        __half2* wpk = (__half2*)(ws + WS_WPK);
        for (int idx = tid; idx < 64 * 128; idx += 1024) {
            int rr = idx >> 7, j2 = idx & 127;
            int o = wb + rr;
            const float* src = wrow_src(o, W_op, W_col, W_hh);
            float2 v = *(const float2*)&src[j2 * 2];
            wpk[(long)o * 128 + j2] = __floats2half2_rn(v.x, v.y);
        }
    }
}

// ==== k_rnn: r10-proven P=8 x R=2 (~42 us) ====
__global__ __launch_bounds__(1024) void k_rnn(const float* __restrict__ Wh,
                      const int* __restrict__ lwi,
                      const float* __restrict__ U, const float* __restrict__ qn,
                      float* __restrict__ ws) {
    __shared__ __attribute__((aligned(16))) float hbuf[2][288];
    __shared__ __attribute__((aligned(16))) float xwb[QLEN][H];
    __shared__ float Z[NNUM][H];
    __shared__ float lg[10];
    int tid = threadIdx.x;
    int g = tid >> 3;
    int p = tid & 7;

    float2 w2[32];
    #pragma unroll
    for (int jj = 0; jj < 32; ++jj)
        w2[jj] = *(const float2*)&Wh[(p * 32 + jj) * H + g * 2];

    {
        const float4* src = (const float4*)&ws[WS_XWB];
        float4* dst = (float4*)&xwb[0][0];
        for (int idx = tid; idx < QLEN * H / 4; idx += 1024) dst[idx] = src[idx];
    }
    if (tid < H) hbuf[0][tid + ((tid >> 5) << 2)] = 0.f;
    __syncthreads();

    int lw0 = lwi[0], lw1 = lwi[1], lw2 = lwi[2], lw3 = lwi[3], lw4 = lwi[4];
    int cur = 0;
    for (int t = 0; t < QLEN; ++t) {
        const float4* hv = (const float4*)&hbuf[cur][p * 36];
        float a0 = 0.f, a1 = 0.f;
        #pragma unroll
        for (int q4 = 0; q4 < 8; ++q4) {
            float4 h4 = hv[q4];
            float2 wa = w2[q4 * 4 + 0];
            float2 wb = w2[q4 * 4 + 1];
            float2 wc = w2[q4 * 4 + 2];
            float2 wd = w2[q4 * 4 + 3];
            a0 += h4.x * wa.x; a1 += h4.x * wa.y;
            a0 += h4.y * wb.x; a1 += h4.y * wb.y;
            a0 += h4.z * wc.x; a1 += h4.z * wc.y;
            a0 += h4.w * wd.x; a1 += h4.w * wd.y;
        }
        a0 = dpp_add<DPP_XOR1>(a0); a0 = dpp_add<DPP_XOR2>(a0); a0 = dpp_add<DPP_HMIR>(a0);
        a1 = dpp_add<DPP_XOR1>(a1); a1 = dpp_add<DPP_XOR2>(a1); a1 = dpp_add<DPP_HMIR>(a1);
        if (p < 2) {
            float s = (p == 0) ? a0 : a1;
            int i = g * 2 + p;
            float hn = fast_tanh(xwb[t][i] + s);
            hbuf[cur ^ 1][i + ((i >> 5) << 2)] = hn;
            if (t == lw0) Z[0][i] = hn;
            if (t == lw1) Z[1][i] = hn;
            if (t == lw2) Z[2][i] = hn;
            if (t == lw3) Z[3][i] = hn;
            if (t == lw4) Z[4][i] = hn;
        }
        __syncthreads();
        cur ^= 1;
    }
    if (tid < H) ws[WS_Q + tid] = hbuf[cur][tid + ((tid >> 5) << 2)];

    int grp = tid >> 5;
    int lane = tid & 31;
    if (grp < 10) {
        int u = grp / 5, n = grp % 5;
        float s = 0.f;
        #pragma unroll
        for (int k = 0; k < 8; ++k) {
            int j = lane + k * 32;
            s += Z[n][j] * U[u * H + j];
        }
        s += __shfl_xor(s, 1);
        s += __shfl_xor(s, 2);
        s += __shfl_xor(s, 4);
        s += __shfl_xor(s, 8);
        s += __shfl_xor(s, 16);
        if (lane == 0) lg[grp] = s;
    }
    __syncthreads();
    if (tid < 2) {
        float m = -1e30f;
        for (int n = 0; n < 5; ++n) m = fmaxf(m, lg[tid * 5 + n]);
        float e[5], s = 0.f;
        for (int n = 0; n < 5; ++n) { e[n] = expf(lg[tid * 5 + n] - m); s += e[n]; }
        float piv = 0.f;
        for (int n = 0; n < 5; ++n) piv += (e[n] / s) * qn[n];
        ws[WS_PIV + (tid == 0 ? 1 : 0)] = piv;   // PIV[0]=g, PIV[1]=l
    }
}

// ==== shared selector body (templated on packed-vs-fp32 streaming) ====
template<bool PACKED>
__device__ __forceinline__ void sel_body(
        const float* __restrict__ W_op, const float* __restrict__ W_col,
        const float* __restrict__ W_hh, const float* __restrict__ op_emb,
        const float* __restrict__ col_emb, float* __restrict__ ws) {
    __shared__ float mlds[73 * 256];     // 73 KB
    __shared__ __attribute__((aligned(16))) float hl[320];
    __shared__ __attribute__((aligned(16))) float uop[320];
    __shared__ __attribute__((aligned(16))) float ucol[320];
    __shared__ float vhh[256];
    __shared__ float Pl[512];
    __shared__ float lgs[80];
    __shared__ float aop_s[16], acol_s[64];
    const int tid = threadIdx.x;
    const int r  = tid >> 4;     // 0..63
    const int p  = tid & 15;
    const int pb = p * 20;
    const __half2* wpk = (const __half2*)(ws + WS_WPK);

    for (int idx = tid; idx < 73 * 256; idx += 1024) mlds[idx] = ws[WS_MOP + idx];
    if (tid < 256) hl[sw(tid)] = ws[WS_Q + tid];
    __syncthreads();

    // prologue: P = W1 @ q  (512 rows, 8 strips)
    {
        float4 q0 = *(const float4*)&hl[pb + 0];
        float4 q1 = *(const float4*)&hl[pb + 4];
        float4 q2 = *(const float4*)&hl[pb + 8];
        float4 q3 = *(const float4*)&hl[pb + 12];
        float qv[16] = {q0.x,q0.y,q0.z,q0.w, q1.x,q1.y,q1.z,q1.w,
                        q2.x,q2.y,q2.z,q2.w, q3.x,q3.y,q3.z,q3.w};
        #pragma unroll 2
        for (int m = 0; m < 8; ++m) {
            int o = m * 64 + r;
            float s = 0.f;
            if (PACKED) {
                const __half2* row = wpk + (long)(768 + o) * 128 + p * 8;
                #pragma unroll
                for (int jj = 0; jj < 8; ++jj) {
                    float2 w = __half22float2(row[jj]);
                    s += w.x * qv[2 * jj] + w.y * qv[2 * jj + 1];
                }
            } else {
                const float* row = (o < 256) ? &W_op[(long)o * 512 + p * 16]
                                             : &W_col[(long)(o - 256) * 512 + p * 16];
                s = dot4(*(const float4*)&row[0], q0) + dot4(*(const float4*)&row[4], q1)
                  + dot4(*(const float4*)&row[8], q2) + dot4(*(const float4*)&row[12], q3);
            }
            s = reduce16(s);
            if (p == 0) Pl[o] = s;
        }
    }
    __syncthreads();
    if (tid < 256) {
        uop[sw(tid)]  = fast_tanh(Pl[tid]);
        ucol[sw(tid)] = fast_tanh(Pl[256 + tid]);
        vhh[tid] = 0.f;
    }
    __syncthreads();

    for (int t = 0; t < T_STEPS; ++t) {
        // logits
        {
            const float* urow = &ucol[pb];
            float4 u0 = *(const float4*)&urow[0];
            float4 u1 = *(const float4*)&urow[4];
            float4 u2 = *(const float4*)&urow[8];
            float4 u3 = *(const float4*)&urow[12];
            const float* erow = &col_emb[r * 256 + p * 16];
            float s = dot4(*(const float4*)&erow[0], u0) + dot4(*(const float4*)&erow[4], u1)
                    + dot4(*(const float4*)&erow[8], u2) + dot4(*(const float4*)&erow[12], u3);
            s = reduce16(s);
            if (p == 0) lgs[NOPS + r] = s;
            if (r < NOPS) {
                const float* vrow = &uop[pb];
                float4 v0 = *(const float4*)&vrow[0];
                float4 v1 = *(const float4*)&vrow[4];
                float4 v2 = *(const float4*)&vrow[8];
                float4 v3 = *(const float4*)&vrow[12];
                const float* orow = &op_emb[r * 256 + p * 16];
                float so = dot4(*(const float4*)&orow[0], v0) + dot4(*(const float4*)&orow[4], v1)
                         + dot4(*(const float4*)&orow[8], v2) + dot4(*(const float4*)&orow[12], v3);
                so = reduce16(so);
                if (p == 0) lgs[r] = so;
            }
        }
        __syncthreads();
        // softmaxes
        if (tid == 0) {
            float m = -1e30f;
            for (int k = 0; k < NOPS; ++k) m = fmaxf(m, lgs[k]);
            float e[NOPS], s = 0.f;
            for (int k = 0; k < NOPS; ++k) { e[k] = expf(lgs[k] - m); s += e[k]; }
            float inv = 1.f / s;
            for (int k = 0; k < NOPS; ++k) {
                float a = e[k] * inv;
                aop_s[k] = a;
                ws[WS_AOP + t * 16 + k] = a;
            }
        }
        if (tid >= 64 && tid < 128) {
            int lane = tid - 64;
            float v = lgs[NOPS + lane];
            float m = v;
            for (int off = 1; off < 64; off <<= 1) m = fmaxf(m, __shfl_xor(m, off));
            float e = expf(v - m);
            float s = e;
            for (int off = 1; off < 64; off <<= 1) s += __shfl_xor(s, off);
            float a = __fdividef(e, s);
            acol_s[lane] = a;
            ws[WS_ACOL + t * COLSN + lane] = a;
        }
        __syncthreads();
        if (t < T_STEPS - 1) {
            // h-update from M (LDS)
            if (tid < 256) {
                float s = vhh[tid];
                #pragma unroll
                for (int k = 0; k < NOPS; ++k) s += aop_s[k] * mlds[k * 256 + tid];
                #pragma unroll 8
                for (int c = 0; c < COLSN; ++c) s += acol_s[c] * mlds[(NOPS + c) * 256 + tid];
                hl[sw(tid)] = fast_tanh(s);
            }
            __syncthreads();
            // stage A for t+1: 768 rows, 12 strips
            {
                float4 h0 = *(const float4*)&hl[pb + 0];
                float4 h1 = *(const float4*)&hl[pb + 4];
                float4 h2 = *(const float4*)&hl[pb + 8];
                float4 h3 = *(const float4*)&hl[pb + 12];
                float hv2[16] = {h0.x,h0.y,h0.z,h0.w, h1.x,h1.y,h1.z,h1.w,
                                 h2.x,h2.y,h2.z,h2.w, h3.x,h3.y,h3.z,h3.w};
                #pragma unroll 2
                for (int m = 0; m < 12; ++m) {
                    int o = m * 64 + r;
                    float s = 0.f;
                    if (PACKED) {
                        const __half2* row = wpk + (long)o * 128 + p * 8;
                        #pragma unroll
                        for (int jj = 0; jj < 8; ++jj) {
                            float2 w = __half22float2(row[jj]);
                            s += w.x * hv2[2 * jj] + w.y * hv2[2 * jj + 1];
                        }
                    } else {
                        const float* row;
                        if (o < 256)      row = &W_op[(long)o * 512 + 256 + p * 16];
                        else if (o < 512) row = &W_col[(long)(o - 256) * 512 + 256 + p * 16];
                        else              row = &W_hh[(long)(o - 512) * 256 + p * 16];
                        s = dot4(*(const float4*)&row[0], h0) + dot4(*(const float4*)&row[4], h1)
                          + dot4(*(const float4*)&row[8], h2) + dot4(*(const float4*)&row[12], h3);
                    }
                    s = reduce16(s);
                    if (p == 0) {
                        if (o < 256)      uop[sw(o)] = fast_tanh(Pl[o] + s);
                        else if (o < 512) ucol[sw(o - 256)] = fast_tanh(Pl[o] + s);
                        else              vhh[o - 512] = s;
                    }
                }
            }
            __syncthreads();
        }
    }
}

__global__ __launch_bounds__(1024) void k_sel2_f16(
        const float* __restrict__ W_op, const float* __restrict__ W_col,
        const float* __restrict__ W_hh, const float* __restrict__ op_emb,
        const float* __restrict__ col_emb, float* __restrict__ ws) {
    sel_body<true>(W_op, W_col, W_hh, op_emb, col_emb, ws);
}
__global__ __launch_bounds__(1024) void k_sel2_f32(
        const float* __restrict__ W_op, const float* __restrict__ W_col,
        const float* __restrict__ W_hh, const float* __restrict__ op_emb,
        const float* __restrict__ col_emb, float* __restrict__ ws) {
    sel_body<false>(W_op, W_col, W_hh, op_emb, col_emb, ws);
}

// ==== k_table: 782 blocks x 512 thr, 2 tiles/block SOFTWARE-PIPELINED
// (both tiles' loads issued before compute) + NONTEMPORAL lookup stores
// (write stream bypasses L2/L3 -> table stays cached). ====
__global__ __launch_bounds__(512) void k_table(const float* __restrict__ table,
                                               float* __restrict__ ws,
                                               float* __restrict__ out) {
    __shared__ __attribute__((aligned(16))) float4 acT4[4][17];
    __shared__ float aop_l[64];
    __shared__ float rs3s[8][16];
    __shared__ float bred[8][8];
    __shared__ int lastblk;
    const int tid = threadIdx.x;
    const int wid = tid >> 6;
    const int lane = tid & 63;
    const int r16 = lane & 15;
    const int q = lane >> 4;

    if (tid < 64) {
        aop_l[tid] = ws[WS_AOP + tid];
        acT4[tid >> 4][tid & 15] = make_float4(
            ws[WS_ACOL + 0 * COLSN + tid], ws[WS_ACOL + 1 * COLSN + tid],
            ws[WS_ACOL + 2 * COLSN + tid], ws[WS_ACOL + 3 * COLSN + tid]);
    }
    __syncthreads();
    const float gp = ws[WS_PIV + 0];
    const float lp = ws[WS_PIV + 1];
    const float ac3 = acT4[q][r16].w;

    long wrow0 = (long)blockIdx.x * 128 + wid * 16;
    long wrow1 = (long)(blockIdx.x + NTBL_BLOCKS) * 128 + wid * 16;
    bool act0 = wrow0 < ROWSN;
    bool act1 = wrow1 < ROWSN;

    // issue ALL loads for both tiles up front (8 x 16B per lane in flight)
    float4 xa0, xa1, xa2, xa3, xb0, xb1, xb2, xb3;
    if (act0) {
        const float* src = table + (wrow0 + r16) * COLSN + q * 16;
        xa0 = *(const float4*)&src[0];
        xa1 = *(const float4*)&src[4];
        xa2 = *(const float4*)&src[8];
        xa3 = *(const float4*)&src[12];
    }
    if (act1) {
        const float* src = table + (wrow1 + r16) * COLSN + q * 16;
        xb0 = *(const float4*)&src[0];
        xb1 = *(const float4*)&src[4];
        xb2 = *(const float4*)&src[8];
        xb3 = *(const float4*)&src[12];
    }

    float dacc[4] = {0,0,0,0}, cacc[4] = {0,0,0,0};

    #define TBL_TILE(X0, X1, X2, X3, WROW, ACT)                                   \
    {                                                                             \
        float cv[4] = {0,0,0,0}, gs[4] = {0,0,0,0}, ls[4] = {0,0,0,0};            \
        if (ACT) {                                                                \
            float xs[16] = {X0.x,X0.y,X0.z,X0.w, X1.x,X1.y,X1.z,X1.w,             \
                            X2.x,X2.y,X2.z,X2.w, X3.x,X3.y,X3.z,X3.w};            \
            _Pragma("unroll")                                                     \
            for (int jj = 0; jj < 16; ++jj) {                                     \
                float x = xs[jj];                                                 \
                float4 a4 = acT4[q][jj];                                          \
                float gt = (x > gp) ? 1.f : 0.f;                                  \
                float lt = (x < lp) ? 1.f : 0.f;                                  \
                cv[0] += x * a4.x;  cv[1] += x * a4.y;                            \
                cv[2] += x * a4.z;  cv[3] += x * a4.w;                            \
                gs[0] += gt * a4.x; gs[1] += gt * a4.y;                           \
                gs[2] += gt * a4.z; gs[3] += gt * a4.w;                           \
                ls[0] += lt * a4.x; ls[1] += lt * a4.y;                           \
                ls[2] += lt * a4.z; ls[3] += lt * a4.w;                           \
            }                                                                     \
        }                                                                         \
        _Pragma("unroll")                                                         \
        for (int k = 0; k < 4; ++k) {                                             \
            cv[k] += __shfl_xor(cv[k], 16); cv[k] += __shfl_xor(cv[k], 32);       \
            gs[k] += __shfl_xor(gs[k], 16); gs[k] += __shfl_xor(gs[k], 32);       \
            ls[k] += __shfl_xor(ls[k], 16); ls[k] += __shfl_xor(ls[k], 32);       \
        }                                                                         \
        float prev1 = 1.f, prev2 = 1.f;                                           \
        _Pragma("unroll")                                                         \
        for (int t = 0; t < 4; ++t) {                                             \
            if (ACT) { dacc[t] += prev1 * cv[t]; cacc[t] += prev1; }              \
            float cg = aop_l[t*16+3], cl = aop_l[t*16+4], cmn = aop_l[t*16+5];    \
            float cmx = aop_l[t*16+6], co = aop_l[t*16+8];                        \
            float cid = aop_l[t*16+0] + aop_l[t*16+1]                             \
                      + aop_l[t*16+2] + aop_l[t*16+7];                            \
            float rsn = cg * gs[t] + cl * ls[t] + cmn * fminf(prev1, prev2)       \
                      + cmx * fmaxf(prev1, prev2) + co + cid * prev1;             \
            prev2 = prev1; prev1 = rsn;                                           \
        }                                                                         \
        if (q == 0 && ACT) rs3s[wid][r16] = prev1 * aop_l[3*16+7];                \
        /* same-wave LDS write->read: program order, no barrier */                \
        if (ACT) {                                                                \
            float* dst = out + 1 + WROW * COLSN;                                  \
            _Pragma("unroll 4")                                                   \
            for (int s = 0; s < 16; ++s)                                          \
                __builtin_nontemporal_store(rs3s[wid][s] * ac3,                   \
                                            &dst[(long)s * COLSN + lane]);        \
        }                                                                         \
    }

    TBL_TILE(xa0, xa1, xa2, xa3, wrow0, act0)
    TBL_TILE(xb0, xb1, xb2, xb3, wrow1, act1)
    #undef TBL_TILE

    float vals[8];
    #pragma unroll
    for (int t = 0; t < 4; ++t) { vals[t] = dacc[t]; vals[4 + t] = cacc[t]; }
    #pragma unroll
    for (int k = 0; k < 8; ++k) vals[k] = reduce16(vals[k]);
    if (lane == 0) {
        #pragma unroll
        for (int k = 0; k < 8; ++k) bred[wid][k] = vals[k];
    }
    __syncthreads();
    if (tid < 8) {
        float s = 0.f;
        #pragma unroll
        for (int w = 0; w < 8; ++w) s += bred[w][tid];
        atomicAdd(&ws[WS_PACC8 + tid], s);
    }
    __syncthreads();

    if (tid == 0) {
        float old = atomicAdd(&ws[WS_TICKET], 1.0f);
        lastblk = ((int)(old + 0.5f) == NTBL_BLOCKS - 1) ? 1 : 0;
    }
    __syncthreads();
    if (lastblk) {
        if (tid < 8) bred[0][tid] = atomicAdd(&ws[WS_PACC8 + tid], 0.f);
        __syncthreads();
        if (tid == 0) {
            float d0 = bred[0][0], d1 = bred[0][1], d2 = bred[0][2], d3 = bred[0][3];
            float c0 = bred[0][4], c1 = bred[0][5], c2 = bred[0][6], c3 = bred[0][7];
            float s0 = aop_l[0]*d0  + aop_l[1]*c0;
            float s1 = aop_l[16]*d1 + aop_l[17]*c1 + aop_l[18]*(0.f - s0);
            float s2 = aop_l[32]*d2 + aop_l[33]*c2 + aop_l[34]*(0.f - s1);
            float s3 = aop_l[48]*d3 + aop_l[49]*c3 + aop_l[50]*(s0 - s2);
            out[0] = s3;
        }
    }
}

extern "C" void kernel_launch(void* const* d_in, const int* in_sizes, int n_in,
                              void* d_out, int out_size, void* d_ws, size_t ws_size,
                              hipStream_t stream) {
    const int*   iq      = (const int*)  d_in[0];
    const float* qn      = (const float*)d_in[1];
    const int*   lwi     = (const int*)  d_in[2];
    const float* table   = (const float*)d_in[3];
    const float* E       = (const float*)d_in[4];
    const float* Wx      = (const float*)d_in[5];
    const float* Wh      = (const float*)d_in[6];
    const float* b       = (const float*)d_in[7];
    const float* W_op    = (const float*)d_in[8];
    const float* op_emb  = (const float*)d_in[9];
    const float* W_col   = (const float*)d_in[10];
    const float* col_emb = (const float*)d_in[11];
    const float* U       = (const float*)d_in[12];
    const float* W_hc    = (const float*)d_in[13];
    const float* W_hh    = (const float*)d_in[14];
    float* out = (float*)d_out;
    float* ws  = (float*)d_ws;

    const bool packed = ws_size >= (size_t)WS_END * sizeof(float);
    int npre = NXW + NMB + (packed ? NPK : 0);

    hipLaunchKernelGGL(k_pre,  dim3(npre), dim3(1024), 0, stream,
                       iq, E, Wx, b, W_hc, op_emb, col_emb, W_op, W_col, W_hh, ws);
    hipLaunchKernelGGL(k_rnn,  dim3(1), dim3(1024), 0, stream, Wh, lwi, U, qn, ws);
    if (packed)
        hipLaunchKernelGGL(k_sel2_f16, dim3(1), dim3(1024), 0, stream,
                           W_op, W_col, W_hh, op_emb, col_emb, ws);
    else
        hipLaunchKernelGGL(k_sel2_f32, dim3(1), dim3(1024), 0, stream,
                           W_op, W_col, W_hh, op_emb, col_emb, ws);
    hipLaunchKernelGGL(k_table, dim3(NTBL_BLOCKS), dim3(512), 0, stream,
                       table, ws, out);
}